// Round 1
// baseline (1238.893 us; speedup 1.0000x reference)
//
#include <hip/hip_runtime.h>

typedef _Float16 half8 __attribute__((ext_vector_type(8)));
typedef _Float16 half4v __attribute__((ext_vector_type(4)));
typedef _Float16 half2v __attribute__((ext_vector_type(2)));
typedef float f32x4 __attribute__((ext_vector_type(4)));
typedef float f32x16 __attribute__((ext_vector_type(16)));
typedef unsigned int u32;
typedef u32 u32x4 __attribute__((ext_vector_type(4)));
typedef int i32x4 __attribute__((ext_vector_type(4)));

#if __has_builtin(__builtin_amdgcn_exp2f)
#define EXP2F(x) __builtin_amdgcn_exp2f(x)
#else
#define EXP2F(x) exp2f(x)
#endif

// fold 1/TEMPERATURE and log2(e) into Q so scores are exp2-ready
#define QSCALE (1.44269504088896340736f * 0.125f)
// column-mask bias folded into MFMA C-init: exp2(s + NEGBIG) == 0 exactly
#define NEGBIG (-16384.0f)

// ---------------- helpers ----------------

__device__ __forceinline__ void gload_lds16(const void* g, void* l) {
    __builtin_amdgcn_global_load_lds(
        (const __attribute__((address_space(1))) u32*)g,
        (__attribute__((address_space(3))) u32*)l, 16, 0, 0);
}

// stage one 16KB tile: 4 waves x 4 issues x 64 lanes x 16B (linear, async)
__device__ __forceinline__ void stage_tile16k(const _Float16* g, _Float16* l,
                                              int wid, int lane) {
#pragma unroll
    for (int i = 0; i < 4; ++i) {
        const int base = (wid * 4 + i) * 1024;
        gload_lds16((const char*)g + base + lane * 16, (char*)l + base);
    }
}

__device__ __forceinline__ u32 pkh(float a, float b) {   // RTE f32x2 -> f16x2
    half2v h; h[0] = (_Float16)a; h[1] = (_Float16)b;
    return __builtin_bit_cast(u32, h);
}

// v_permlane32_swap_b32: rows 32-63 of first operand <-> rows 0-31 of second.
// swap32(cA,cB): cA -> {lo:own cA, hi:partner cB} (=w0), cB -> {lo:partner cA, hi:own cB} (=w2)
__device__ __forceinline__ void swap32(u32 &a, u32 &b) {
    asm volatile("v_permlane32_swap_b32 %0, %1" : "+v"(a), "+v"(b));
}

// ---------------- kernel0: K,V -> fp16 workspace tiles (XOR-swizzled) ----------------
// Kws tile (per bh,kc, 16KB): byte L: row r=L>>7 (key 0..127), b=L&127,
//   cb = b ^ ((r&7)<<4), content = (half)K[r][cb>>1 ...]
// Vws tile: byte L: row r=L>>8 (d 0..63), b=L&255, cb = b ^ ((r&7)<<4),
//   content = (half)V[cb>>1 + j][d=r]  (transposed)
__global__ __launch_bounds__(256, 2)
void prep_kv(const float* __restrict__ kg_, const float* __restrict__ vg_,
             _Float16* __restrict__ kws_, _Float16* __restrict__ vws_)
{
    __shared__ float tile[128 * 68];
    const int tid = threadIdx.x;
    const int bh  = blockIdx.x & 31;
    const int kc  = blockIdx.x >> 5;
    const float* kg = kg_ + ((size_t)bh * 2048 + kc * 128) * 64;
    const float* vg = vg_ + ((size_t)bh * 2048 + kc * 128) * 64;
    _Float16* kt = kws_ + ((size_t)bh * 16 + kc) * 8192;
    _Float16* vt = vws_ + ((size_t)bh * 16 + kc) * 8192;

    // ---- K ----
#pragma unroll
    for (int i = 0; i < 8; ++i) {
        int f = tid + 256 * i;                 // 2048 float4s
        int r = f >> 4, c4 = f & 15;
        f32x4 x = *reinterpret_cast<const f32x4*>(kg + r * 64 + c4 * 4);
        *reinterpret_cast<f32x4*>(&tile[r * 68 + c4 * 4]) = x;
    }
    __syncthreads();
#pragma unroll
    for (int i = 0; i < 4; ++i) {
        int s16 = tid + 256 * i;               // 16B unit, [0,1024)
        int r = s16 >> 3, u = s16 & 7;
        int cb = (u * 16) ^ ((r & 7) << 4);
        int d0 = cb >> 1;
        f32x4 x0 = *reinterpret_cast<const f32x4*>(&tile[r * 68 + d0]);
        f32x4 x1 = *reinterpret_cast<const f32x4*>(&tile[r * 68 + d0 + 4]);
        half8 h;
#pragma unroll
        for (int j = 0; j < 4; ++j) { h[j] = (_Float16)x0[j]; h[4 + j] = (_Float16)x1[j]; }
        __builtin_nontemporal_store(h, reinterpret_cast<half8*>(kt + s16 * 8));
    }
    __syncthreads();
    // ---- V (transposed) ----
#pragma unroll
    for (int i = 0; i < 8; ++i) {
        int f = tid + 256 * i;
        int r = f >> 4, c4 = f & 15;
        f32x4 x = *reinterpret_cast<const f32x4*>(vg + r * 64 + c4 * 4);
        *reinterpret_cast<f32x4*>(&tile[r * 68 + c4 * 4]) = x;
    }
    __syncthreads();
#pragma unroll
    for (int i = 0; i < 4; ++i) {
        int s16 = tid + 256 * i;
        int r = s16 >> 4, u = s16 & 15;        // r = d (0..63)
        int cb = (u * 16) ^ ((r & 7) << 4);
        int k0 = cb >> 1;
        half8 h;
#pragma unroll
        for (int j = 0; j < 8; ++j) h[j] = (_Float16)tile[(k0 + j) * 68 + r];
        __builtin_nontemporal_store(h, reinterpret_cast<half8*>(vt + s16 * 8));
    }
}

// ---------------- kernel1: row sums of exp2(masked scores) ----------------
__global__ __launch_bounds__(256, 2)
void attn_sums(const float* __restrict__ qg_, const _Float16* __restrict__ kws_,
               const int* __restrict__ mg_, float* __restrict__ rsums_)
{
    __shared__ _Float16 Kb[2][8192];
    __shared__ float biasF[2048];
    const int tid = threadIdx.x, wid = tid >> 6, lane = tid & 63;
    const int l31 = lane & 31, hi = lane >> 5;
    const int bh = blockIdx.x & 31, qt = blockIdx.x >> 5;
    const int* mg = mg_ + (bh >> 4) * 2048;
    const _Float16* ktiles = kws_ + (size_t)bh * 16 * 8192;

    // Q fragments straight from global (one-time)
    const float* qrow = qg_ + ((size_t)bh * 2048 + qt * 128 + wid * 32 + l31) * 64;
    half8 qf[4];
#pragma unroll
    for (int ks = 0; ks < 4; ++ks) {
        f32x4 x0 = *reinterpret_cast<const f32x4*>(qrow + ks * 16 + hi * 8);
        f32x4 x1 = *reinterpret_cast<const f32x4*>(qrow + ks * 16 + hi * 8 + 4);
#pragma unroll
        for (int j = 0; j < 4; ++j) {
            qf[ks][j]     = (_Float16)(x0[j] * QSCALE);
            qf[ks][4 + j] = (_Float16)(x1[j] * QSCALE);
        }
    }
    // column bias table
#pragma unroll
    for (int i = 0; i < 2; ++i) {
        int j = (tid + 256 * i) * 4;
        i32x4 m = *reinterpret_cast<const i32x4*>(mg + j);
        f32x4 bv;
        bv[0] = m[0] ? NEGBIG : 0.f; bv[1] = m[1] ? NEGBIG : 0.f;
        bv[2] = m[2] ? NEGBIG : 0.f; bv[3] = m[3] ? NEGBIG : 0.f;
        *reinterpret_cast<f32x4*>(&biasF[j]) = bv;
    }
    stage_tile16k(ktiles, Kb[0], wid, lane);
    __syncthreads();

    float lsum = 0.f;
    _Float16 *cur = Kb[0], *nxt = Kb[1];
    for (int kc = 0; kc < 16; ++kc) {
        if (kc < 15) stage_tile16k(ktiles + (size_t)(kc + 1) * 8192, nxt, wid, lane);
        asm volatile("" ::: "memory");
#pragma unroll
        for (int kb = 0; kb < 4; ++kb) {
            f32x16 acc;
#pragma unroll
            for (int g = 0; g < 4; ++g) {
                f32x4 bv = *reinterpret_cast<const f32x4*>(
                    &biasF[kc * 128 + kb * 32 + g * 8 + hi * 4]);
                acc[4*g+0] = bv[0]; acc[4*g+1] = bv[1];
                acc[4*g+2] = bv[2]; acc[4*g+3] = bv[3];
            }
            const int row = kb * 32 + l31;
            const char* rbase = (const char*)cur + row * 128;
            const int swz = (row & 7) << 4;
#pragma unroll
            for (int ks = 0; ks < 4; ++ks) {
                half8 kf = *reinterpret_cast<const half8*>(rbase + ((ks * 32 + hi * 16) ^ swz));
                acc = __builtin_amdgcn_mfma_f32_32x32x16_f16(kf, qf[ks], acc, 0, 0, 0);
            }
#pragma unroll
            for (int r = 0; r < 16; ++r) lsum += EXP2F(acc[r]);
        }
        __syncthreads();     // also drains the async stage loads (vmcnt 0)
        _Float16* t = cur; cur = nxt; nxt = t;
    }
    lsum += __shfl_xor(lsum, 32, 64);
    if (hi == 0)
        rsums_[(size_t)bh * 2048 + qt * 128 + wid * 32 + l31] = lsum;
}

// ---------------- kernel2: single pass, attn + O ----------------
__global__ __launch_bounds__(256, 2)
void attn_main(const float* __restrict__ qg_, const _Float16* __restrict__ kws_,
               const _Float16* __restrict__ vws_, const int* __restrict__ mg_,
               const float* __restrict__ rsums_,
               float* __restrict__ outg_, float* __restrict__ attng_)
{
    __shared__ _Float16 Kb[2][8192];
    __shared__ _Float16 Vb[2][8192];
    __shared__ float biasF[2048];
    const int tid = threadIdx.x, wid = tid >> 6, lane = tid & 63;
    const int l31 = lane & 31, hi = lane >> 5;
    const int bh = blockIdx.x & 31, qt = blockIdx.x >> 5;
    const int* mg = mg_ + (bh >> 4) * 2048;
    const _Float16* ktiles = kws_ + (size_t)bh * 16 * 8192;
    const _Float16* vtiles = vws_ + (size_t)bh * 16 * 8192;
    const int qrow_l = qt * 128 + wid * 32 + l31;

    const float* qrow = qg_ + ((size_t)bh * 2048 + qrow_l) * 64;
    half8 qf[4];
#pragma unroll
    for (int ks = 0; ks < 4; ++ks) {
        f32x4 x0 = *reinterpret_cast<const f32x4*>(qrow + ks * 16 + hi * 8);
        f32x4 x1 = *reinterpret_cast<const f32x4*>(qrow + ks * 16 + hi * 8 + 4);
#pragma unroll
        for (int j = 0; j < 4; ++j) {
            qf[ks][j]     = (_Float16)(x0[j] * QSCALE);
            qf[ks][4 + j] = (_Float16)(x1[j] * QSCALE);
        }
    }
#pragma unroll
    for (int i = 0; i < 2; ++i) {
        int j = (tid + 256 * i) * 4;
        i32x4 m = *reinterpret_cast<const i32x4*>(mg + j);
        f32x4 bv;
        bv[0] = m[0] ? NEGBIG : 0.f; bv[1] = m[1] ? NEGBIG : 0.f;
        bv[2] = m[2] ? NEGBIG : 0.f; bv[3] = m[3] ? NEGBIG : 0.f;
        *reinterpret_cast<f32x4*>(&biasF[j]) = bv;
    }

    const float rs = rsums_[(size_t)bh * 2048 + qrow_l];
    const int   rm = mg[qrow_l];
    const bool uni = (rm != 0) || !(rs > 0.f);
    const float rscale = uni ? 0.f : 1.f / rs;
    const float radd   = uni ? (1.0f / 2048.0f) : 0.f;

    stage_tile16k(ktiles, Kb[0], wid, lane);
    stage_tile16k(vtiles, Vb[0], wid, lane);
    __syncthreads();

    f32x16 Oacc0, Oacc1;
#pragma unroll
    for (int r = 0; r < 16; ++r) { Oacc0[r] = 0.f; Oacc1[r] = 0.f; }

    float* attnrow = attng_ + ((size_t)bh * 2048 + qrow_l) * 2048;
    _Float16 *curK = Kb[0], *nxtK = Kb[1], *curV = Vb[0], *nxtV = Vb[1];

    for (int kc = 0; kc < 16; ++kc) {
        if (kc < 15) {
            stage_tile16k(ktiles + (size_t)(kc + 1) * 8192, nxtK, wid, lane);
            stage_tile16k(vtiles + (size_t)(kc + 1) * 8192, nxtV, wid, lane);
        }
        asm volatile("" ::: "memory");   // keep stage issues ahead of compute/stores
#pragma unroll
        for (int kb = 0; kb < 4; ++kb) {
            // S^T = K.Q (swapped): lane = q (l31), regs = k rows
            f32x16 acc;
#pragma unroll
            for (int g = 0; g < 4; ++g) {
                f32x4 bv = *reinterpret_cast<const f32x4*>(
                    &biasF[kc * 128 + kb * 32 + g * 8 + hi * 4]);
                acc[4*g+0] = bv[0]; acc[4*g+1] = bv[1];
                acc[4*g+2] = bv[2]; acc[4*g+3] = bv[3];
            }
            const int row = kb * 32 + l31;
            const char* rbase = (const char*)curK + row * 128;
            const int swz = (row & 7) << 4;
#pragma unroll
            for (int ks = 0; ks < 4; ++ks) {
                half8 kf = *reinterpret_cast<const half8*>(rbase + ((ks * 32 + hi * 16) ^ swz));
                acc = __builtin_amdgcn_mfma_f32_32x32x16_f16(kf, qf[ks], acc, 0, 0, 0);
            }
            // normalized P, straight to f32 attn stores (nt), k = (r&3)+8*(r>>2)+4*hi
            float p[16];
#pragma unroll
            for (int r = 0; r < 16; ++r) p[r] = EXP2F(acc[r]) * rscale + radd;
#pragma unroll
            for (int g = 0; g < 4; ++g) {
                f32x4 v; v[0] = p[4*g]; v[1] = p[4*g+1]; v[2] = p[4*g+2]; v[3] = p[4*g+3];
                __builtin_nontemporal_store(v, reinterpret_cast<f32x4*>(
                    attnrow + kc * 128 + kb * 32 + g * 8 + hi * 4));
            }
            // T12: in-register P -> fp16 A-frags (no LDS round-trip)
#pragma unroll
            for (int s = 0; s < 2; ++s) {
                u32 cA = pkh(p[8*s + 0], p[8*s + 1]);
                u32 dA = pkh(p[8*s + 2], p[8*s + 3]);
                u32 cB = pkh(p[8*s + 4], p[8*s + 5]);
                u32 dB = pkh(p[8*s + 6], p[8*s + 7]);
                swap32(cA, cB);   // cA -> w0, cB -> w2
                swap32(dA, dB);   // dA -> w1, dB -> w3
                u32x4 wv; wv[0] = cA; wv[1] = dA; wv[2] = cB; wv[3] = dB;
                half8 af = __builtin_bit_cast(half8, wv);
#pragma unroll
                for (int nd = 0; nd < 2; ++nd) {
                    const int vrow = nd * 32 + l31;
                    half8 bf = *reinterpret_cast<const half8*>(
                        (const char*)curV + vrow * 256 +
                        ((kb * 64 + s * 32 + hi * 16) ^ ((vrow & 7) << 4)));
                    if (nd == 0) Oacc0 = __builtin_amdgcn_mfma_f32_32x32x16_f16(af, bf, Oacc0, 0, 0, 0);
                    else         Oacc1 = __builtin_amdgcn_mfma_f32_32x32x16_f16(af, bf, Oacc1, 0, 0, 0);
                }
            }
        }
        if (kc < 15) {
            // counted vmcnt: waits the 8 stage loads, leaves this chunk's 16 nt stores in flight
            asm volatile("s_waitcnt vmcnt(16) lgkmcnt(0)" ::: "memory");
            __builtin_amdgcn_s_barrier();
            _Float16* t;
            t = curK; curK = nxtK; nxtK = t;
            t = curV; curV = nxtV; nxtV = t;
        }
    }

    float* outg = outg_ + ((size_t)bh * 2048 + qt * 128) * 64;
#pragma unroll
    for (int r = 0; r < 16; ++r) {
        int q_l = wid * 32 + (r & 3) + 8 * (r >> 2) + 4 * hi;
        __builtin_nontemporal_store(Oacc0[r], outg + (size_t)q_l * 64 + l31);
        __builtin_nontemporal_store(Oacc1[r], outg + (size_t)q_l * 64 + 32 + l31);
    }
}

// ---------------- fallback: previous verified kernel (used if ws too small) ----------------
__global__ __launch_bounds__(256, 2)
void attn_fused(const float* __restrict__ qg_, const float* __restrict__ kg_,
                const float* __restrict__ vg_, const int* __restrict__ mg_,
                float* __restrict__ outg_, float* __restrict__ attng_)
{
    constexpr int N = 2048, D = 64, TM = 128, BK = 128, NCH = 16;
    constexpr int QS = 72, KS = 72, VTS = 136, PS = 72;
    constexpr float INVN = 1.0f / 2048.0f;

    __shared__ _Float16 Qs[TM * QS];
    __shared__ _Float16 Ksh[BK * KS];
    __shared__ _Float16 Vts[D * VTS];
    __shared__ _Float16 Ps[TM * PS];
    __shared__ unsigned char cm[N];

    const int tid  = threadIdx.x;
    const int wid  = tid >> 6;
    const int lane = tid & 63;
    const int quad = lane >> 4;
    const int l15  = lane & 15;

    const int bh = blockIdx.x & 31;
    const int qt = blockIdx.x >> 5;
    const int b  = bh >> 4;

    const float* qg = qg_ + ((size_t)bh * N + qt * TM) * D;
    const float* kg = kg_ + (size_t)bh * N * D;
    const float* vg = vg_ + (size_t)bh * N * D;
    const int*   mg = mg_ + (size_t)b * N;
    float* attng = attng_ + ((size_t)bh * N + (size_t)qt * TM) * N;
    float* outg  = outg_  + ((size_t)bh * N + qt * TM) * D;

#pragma unroll
    for (int i = 0; i < 8; ++i) {
        int f = tid + 256 * i;
        int row = f >> 4, d = (f & 15) * 4;
        float4 x = *reinterpret_cast<const float4*>(qg + (size_t)row * D + d);
        half4v hv;
        hv[0] = (_Float16)(x.x * QSCALE);
        hv[1] = (_Float16)(x.y * QSCALE);
        hv[2] = (_Float16)(x.z * QSCALE);
        hv[3] = (_Float16)(x.w * QSCALE);
        *reinterpret_cast<half4v*>(&Qs[row * QS + d]) = hv;
        cm[f] = (unsigned char)(mg[f] ? 0 : 1);
    }

    float rowm[2][4];
#pragma unroll
    for (int mb = 0; mb < 2; ++mb)
#pragma unroll
        for (int r = 0; r < 4; ++r) {
            int row = qt * TM + wid * 32 + mb * 16 + quad * 4 + r;
            rowm[mb][r] = (float)mg[row];
        }

    __syncthreads();

    half8 qfr[2][2];
#pragma unroll
    for (int mb = 0; mb < 2; ++mb)
#pragma unroll
        for (int ks = 0; ks < 2; ++ks)
            qfr[mb][ks] = *reinterpret_cast<half8*>(
                &Qs[(wid * 32 + mb * 16 + l15) * QS + ks * 32 + quad * 8]);

    float lsum[2][4] = {{0,0,0,0},{0,0,0,0}};

    for (int kc = 0; kc < NCH; ++kc) {
        __syncthreads();
#pragma unroll
        for (int i = 0; i < 8; ++i) {
            int f = tid + 256 * i;
            int row = f >> 4, d = (f & 15) * 4;
            float4 x = *reinterpret_cast<const float4*>(kg + (size_t)(kc * BK + row) * D + d);
            half4v hv;
            hv[0] = (_Float16)x.x; hv[1] = (_Float16)x.y;
            hv[2] = (_Float16)x.z; hv[3] = (_Float16)x.w;
            *reinterpret_cast<half4v*>(&Ksh[row * KS + d]) = hv;
        }
        __syncthreads();

#pragma unroll
        for (int mb = 0; mb < 2; ++mb) {
#pragma unroll
            for (int nb = 0; nb < 8; ++nb) {
                f32x4 acc = {0.f, 0.f, 0.f, 0.f};
#pragma unroll
                for (int ks = 0; ks < 2; ++ks) {
                    half8 bfr = *reinterpret_cast<half8*>(
                        &Ksh[(nb * 16 + l15) * KS + ks * 32 + quad * 8]);
                    acc = __builtin_amdgcn_mfma_f32_16x16x32_f16(qfr[mb][ks], bfr, acc, 0, 0, 0);
                }
                float cmf = (float)cm[kc * BK + nb * 16 + l15];
#pragma unroll
                for (int r = 0; r < 4; ++r)
                    lsum[mb][r] += cmf * EXP2F(acc[r]);
            }
        }
    }

#pragma unroll
    for (int mb = 0; mb < 2; ++mb)
#pragma unroll
        for (int r = 0; r < 4; ++r) {
            float s = lsum[mb][r];
            s += __shfl_xor(s, 1, 64);
            s += __shfl_xor(s, 2, 64);
            s += __shfl_xor(s, 4, 64);
            s += __shfl_xor(s, 8, 64);
            lsum[mb][r] = s;
        }

    float rscale[2][4], radd[2][4];
#pragma unroll
    for (int mb = 0; mb < 2; ++mb)
#pragma unroll
        for (int r = 0; r < 4; ++r) {
            bool uni = (rowm[mb][r] != 0.0f) || !(lsum[mb][r] > 0.0f);
            rscale[mb][r] = uni ? 0.0f : 1.0f / lsum[mb][r];
            radd[mb][r]   = uni ? INVN : 0.0f;
        }

    f32x4 Oacc[2][4];
#pragma unroll
    for (int mb = 0; mb < 2; ++mb)
#pragma unroll
        for (int nd = 0; nd < 4; ++nd)
            Oacc[mb][nd] = (f32x4){0.f, 0.f, 0.f, 0.f};

    for (int kc = 0; kc < NCH; ++kc) {
        __syncthreads();
#pragma unroll
        for (int i = 0; i < 8; ++i) {
            int f = tid + 256 * i;
            int row = f >> 4, d = (f & 15) * 4;
            float4 x = *reinterpret_cast<const float4*>(kg + (size_t)(kc * BK + row) * D + d);
            half4v hv;
            hv[0] = (_Float16)x.x; hv[1] = (_Float16)x.y;
            hv[2] = (_Float16)x.z; hv[3] = (_Float16)x.w;
            *reinterpret_cast<half4v*>(&Ksh[row * KS + d]) = hv;
        }
#pragma unroll
        for (int rr = 0; rr < 4; ++rr) {
            int key0 = rr * 32 + wid * 8;
            half8 hh;
#pragma unroll
            for (int j = 0; j < 8; ++j)
                hh[j] = (_Float16)vg[(size_t)(kc * BK + key0 + j) * D + lane];
            *reinterpret_cast<half8*>(&Vts[lane * VTS + key0]) = hh;
        }
        __syncthreads();

        f32x4 S[2][8];
#pragma unroll
        for (int mb = 0; mb < 2; ++mb)
#pragma unroll
            for (int nb = 0; nb < 8; ++nb) {
                f32x4 acc = {0.f, 0.f, 0.f, 0.f};
#pragma unroll
                for (int ks = 0; ks < 2; ++ks) {
                    half8 bfr = *reinterpret_cast<half8*>(
                        &Ksh[(nb * 16 + l15) * KS + ks * 32 + quad * 8]);
                    acc = __builtin_amdgcn_mfma_f32_16x16x32_f16(qfr[mb][ks], bfr, acc, 0, 0, 0);
                }
                S[mb][nb] = acc;
            }

#pragma unroll
        for (int h = 0; h < 2; ++h) {
#pragma unroll
            for (int nb2 = 0; nb2 < 4; ++nb2) {
                int nb = h * 4 + nb2;
                float cmf = (float)cm[kc * BK + nb * 16 + l15];
#pragma unroll
                for (int mb = 0; mb < 2; ++mb) {
#pragma unroll
                    for (int r = 0; r < 4; ++r) {
                        float p = cmf * EXP2F(S[mb][nb][r]) * rscale[mb][r] + radd[mb][r];
                        Ps[(wid * 32 + mb * 16 + quad * 4 + r) * PS + nb2 * 16 + l15] = (_Float16)p;
                    }
                }
            }
            asm volatile("s_waitcnt lgkmcnt(0)" ::: "memory");

#pragma unroll
            for (int r8 = 0; r8 < 8; ++r8) {
                int rl = r8 * 4 + quad;
                half4v ph = *reinterpret_cast<half4v*>(
                    &Ps[(wid * 32 + rl) * PS + l15 * 4]);
                f32x4 pf;
                pf[0] = (float)ph[0]; pf[1] = (float)ph[1];
                pf[2] = (float)ph[2]; pf[3] = (float)ph[3];
                float* dst = attng + (size_t)(wid * 32 + rl) * N + kc * BK + h * 64 + l15 * 4;
                __builtin_nontemporal_store(pf, reinterpret_cast<f32x4*>(dst));
            }

#pragma unroll
            for (int ks = 0; ks < 2; ++ks) {
                half8 af[2];
#pragma unroll
                for (int mb = 0; mb < 2; ++mb)
                    af[mb] = *reinterpret_cast<half8*>(
                        &Ps[(wid * 32 + mb * 16 + l15) * PS + ks * 32 + quad * 8]);
#pragma unroll
                for (int nd = 0; nd < 4; ++nd) {
                    half8 bfr = *reinterpret_cast<half8*>(
                        &Vts[(nd * 16 + l15) * VTS + h * 64 + ks * 32 + quad * 8]);
#pragma unroll
                    for (int mb = 0; mb < 2; ++mb)
                        Oacc[mb][nd] = __builtin_amdgcn_mfma_f32_16x16x32_f16(af[mb], bfr, Oacc[mb][nd], 0, 0, 0);
                }
            }
        }
    }

#pragma unroll
    for (int mb = 0; mb < 2; ++mb)
#pragma unroll
        for (int nd = 0; nd < 4; ++nd)
#pragma unroll
            for (int r = 0; r < 4; ++r)
                __builtin_nontemporal_store(
                    Oacc[mb][nd][r],
                    outg + (size_t)(wid * 32 + mb * 16 + quad * 4 + r) * D + nd * 16 + l15);
}

// ---------------- launch ----------------
extern "C" void kernel_launch(void* const* d_in, const int* in_sizes, int n_in,
                              void* d_out, int out_size, void* d_ws, size_t ws_size,
                              hipStream_t stream) {
    const float* q   = (const float*)d_in[0];
    const float* k   = (const float*)d_in[1];
    const float* v   = (const float*)d_in[2];
    const int*   msk = (const int*)d_in[3];
    float* out  = (float*)d_out;
    float* attn = out + (size_t)2 * 16 * 2048 * 64;   // output first, then attn

    const size_t kv_halves = (size_t)32 * 2048 * 64;          // per tensor
    const size_t need = kv_halves * 2 * sizeof(_Float16)      // Kws + Vws
                      + (size_t)32 * 2048 * sizeof(float);    // row sums
    if (d_ws != nullptr && ws_size >= need) {
        _Float16* kws = (_Float16*)d_ws;
        _Float16* vws = kws + kv_halves;
        float* rsums  = (float*)(vws + kv_halves);
        hipLaunchKernelGGL(prep_kv,   dim3(512), dim3(256), 0, stream, k, v, kws, vws);
        hipLaunchKernelGGL(attn_sums, dim3(512), dim3(256), 0, stream, q, kws, msk, rsums);
        hipLaunchKernelGGL(attn_main, dim3(512), dim3(256), 0, stream,
                           q, kws, vws, msk, rsums, out, attn);
    } else {
        hipLaunchKernelGGL(attn_fused, dim3(512), dim3(256), 0, stream,
                           q, k, v, msk, out, attn);
    }
}

// Round 2
// 689.081 us; speedup vs baseline: 1.7979x; 1.7979x over previous
//
#include <hip/hip_runtime.h>

typedef _Float16 half8 __attribute__((ext_vector_type(8)));
typedef _Float16 half4v __attribute__((ext_vector_type(4)));
typedef _Float16 half2v __attribute__((ext_vector_type(2)));
typedef float f32x4 __attribute__((ext_vector_type(4)));
typedef float f32x16 __attribute__((ext_vector_type(16)));
typedef unsigned int u32;
typedef u32 u32x2 __attribute__((ext_vector_type(2)));
typedef u32 u32x4 __attribute__((ext_vector_type(4)));
typedef int i32x4 __attribute__((ext_vector_type(4)));

#if __has_builtin(__builtin_amdgcn_exp2f)
#define EXP2F(x) __builtin_amdgcn_exp2f(x)
#else
#define EXP2F(x) exp2f(x)
#endif

// fold 1/TEMPERATURE and log2(e) into Q so scores are exp2-ready
#define QSCALE (1.44269504088896340736f * 0.125f)
// column-mask bias folded into MFMA C-init: exp2(s + NEGBIG) == 0 exactly
#define NEGBIG (-16384.0f)

// ---------------- helpers ----------------

__device__ __forceinline__ void gload_lds16(const void* g, void* l) {
    __builtin_amdgcn_global_load_lds(
        (const __attribute__((address_space(1))) u32*)g,
        (__attribute__((address_space(3))) u32*)l, 16, 0, 0);
}

// stage one 16KB tile: 4 waves x 4 issues x 64 lanes x 16B (linear, async)
__device__ __forceinline__ void stage_tile16k(const _Float16* g, _Float16* l,
                                              int wid, int lane) {
#pragma unroll
    for (int i = 0; i < 4; ++i) {
        const int base = (wid * 4 + i) * 1024;
        gload_lds16((const char*)g + base + lane * 16, (char*)l + base);
    }
}

__device__ __forceinline__ u32 pkh(float a, float b) {   // RTE f32x2 -> f16x2
    half2v h; h[0] = (_Float16)a; h[1] = (_Float16)b;
    return __builtin_bit_cast(u32, h);
}

// v_permlane32_swap_b32: rows 32-63 of first operand <-> rows 0-31 of second.
__device__ __forceinline__ void swap32(u32 &a, u32 &b) {
    asm volatile("v_permlane32_swap_b32 %0, %1" : "+v"(a), "+v"(b));
}

// ---- conflict-free tile layouts (pre-permuted in global by prep_kv) ----
// K tile 16KB: k-row r (0..127), byte c (0..127):
//   L = (r>>2)*512 + (r&3)*128 + (c ^ (((r>>2)&7)<<4))
//   -> a wave's 32 rows (l31) at fixed c map to 32 DISTINCT 16B slots.
// V tile 16KB: d-row d (0..63), byte c (0..255):
//   L = (d>>1)*512 + (d&1)*256 + (c ^ (((d>>1)&15)<<4))

// ---------------- kernel0: K,V -> fp16 workspace tiles ----------------
__global__ __launch_bounds__(256, 2)
void prep_kv(const float* __restrict__ kg_, const float* __restrict__ vg_,
             _Float16* __restrict__ kws_, _Float16* __restrict__ vws_)
{
    __shared__ float tile[128 * 68];
    const int tid = threadIdx.x;
    const int bh  = blockIdx.x & 31;
    const int kc  = blockIdx.x >> 5;
    const float* kg = kg_ + ((size_t)bh * 2048 + kc * 128) * 64;
    const float* vg = vg_ + ((size_t)bh * 2048 + kc * 128) * 64;
    _Float16* kt = kws_ + ((size_t)bh * 16 + kc) * 8192;
    _Float16* vt = vws_ + ((size_t)bh * 16 + kc) * 8192;

    // ---- K ----
#pragma unroll
    for (int i = 0; i < 8; ++i) {
        int f = tid + 256 * i;                 // 2048 float4s
        int r = f >> 4, c4 = f & 15;
        f32x4 x = *reinterpret_cast<const f32x4*>(kg + r * 64 + c4 * 4);
        *reinterpret_cast<f32x4*>(&tile[r * 68 + c4 * 4]) = x;
    }
    __syncthreads();
#pragma unroll
    for (int i = 0; i < 4; ++i) {
        int s16 = tid + 256 * i;               // 16B unit, [0,1024)
        int R5 = s16 >> 5;                     // r>>2
        int r  = R5 * 4 + ((s16 >> 3) & 3);
        int c  = ((s16 & 7) << 4) ^ ((R5 & 7) << 4);
        int d0 = c >> 1;                       // half index, multiple of 8
        f32x4 x0 = *reinterpret_cast<const f32x4*>(&tile[r * 68 + d0]);
        f32x4 x1 = *reinterpret_cast<const f32x4*>(&tile[r * 68 + d0 + 4]);
        half8 h;
#pragma unroll
        for (int j = 0; j < 4; ++j) { h[j] = (_Float16)x0[j]; h[4 + j] = (_Float16)x1[j]; }
        __builtin_nontemporal_store(h, reinterpret_cast<half8*>(kt + s16 * 8));
    }
    __syncthreads();
    // ---- V (transposed) ----
#pragma unroll
    for (int i = 0; i < 8; ++i) {
        int f = tid + 256 * i;
        int r = f >> 4, c4 = f & 15;
        f32x4 x = *reinterpret_cast<const f32x4*>(vg + r * 64 + c4 * 4);
        *reinterpret_cast<f32x4*>(&tile[r * 68 + c4 * 4]) = x;
    }
    __syncthreads();
#pragma unroll
    for (int i = 0; i < 4; ++i) {
        int s16 = tid + 256 * i;
        int R5 = s16 >> 5;                     // d>>1
        int d  = R5 * 2 + ((s16 >> 4) & 1);
        int c  = ((s16 & 15) << 4) ^ ((R5 & 15) << 4);
        int k0 = c >> 1;                       // key index, multiple of 8
        half8 h;
#pragma unroll
        for (int j = 0; j < 8; ++j) h[j] = (_Float16)tile[(k0 + j) * 68 + d];
        __builtin_nontemporal_store(h, reinterpret_cast<half8*>(vt + s16 * 8));
    }
}

// ---------------- kernel1: row sums of exp2(masked scores) ----------------
__global__ __launch_bounds__(256, 2)
void attn_sums(const float* __restrict__ qg_, const _Float16* __restrict__ kws_,
               const int* __restrict__ mg_, float* __restrict__ rsums_)
{
    __shared__ _Float16 Kb[2][8192];
    __shared__ float biasF[2048];
    const int tid = threadIdx.x, wid = tid >> 6, lane = tid & 63;
    const int l31 = lane & 31, hi = lane >> 5;
    const int bh = blockIdx.x & 31, qt = blockIdx.x >> 5;
    const int* mg = mg_ + (bh >> 4) * 2048;
    const _Float16* ktiles = kws_ + (size_t)bh * 16 * 8192;

    const float* qrow = qg_ + ((size_t)bh * 2048 + qt * 128 + wid * 32 + l31) * 64;
    half8 qf[4];
#pragma unroll
    for (int ks = 0; ks < 4; ++ks) {
        f32x4 x0 = *reinterpret_cast<const f32x4*>(qrow + ks * 16 + hi * 8);
        f32x4 x1 = *reinterpret_cast<const f32x4*>(qrow + ks * 16 + hi * 8 + 4);
#pragma unroll
        for (int j = 0; j < 4; ++j) {
            qf[ks][j]     = (_Float16)(x0[j] * QSCALE);
            qf[ks][4 + j] = (_Float16)(x1[j] * QSCALE);
        }
    }
#pragma unroll
    for (int i = 0; i < 2; ++i) {
        int j = (tid + 256 * i) * 4;
        i32x4 m = *reinterpret_cast<const i32x4*>(mg + j);
        f32x4 bv;
        bv[0] = m[0] ? NEGBIG : 0.f; bv[1] = m[1] ? NEGBIG : 0.f;
        bv[2] = m[2] ? NEGBIG : 0.f; bv[3] = m[3] ? NEGBIG : 0.f;
        *reinterpret_cast<f32x4*>(&biasF[j]) = bv;
    }
    stage_tile16k(ktiles, Kb[0], wid, lane);
    __syncthreads();

    const int rbK = (l31 >> 2) * 512 + (l31 & 3) * 128;
    const int swK = (l31 >> 2) << 4;

    float lsum = 0.f;
    _Float16 *cur = Kb[0], *nxt = Kb[1];
    for (int kc = 0; kc < 16; ++kc) {
        if (kc < 15) stage_tile16k(ktiles + (size_t)(kc + 1) * 8192, nxt, wid, lane);
        asm volatile("" ::: "memory");
        const char* curb = (const char*)cur;
#pragma unroll
        for (int kb = 0; kb < 4; ++kb) {
            f32x16 acc;
#pragma unroll
            for (int g = 0; g < 4; ++g) {
                f32x4 bv = *reinterpret_cast<const f32x4*>(
                    &biasF[kc * 128 + kb * 32 + g * 8 + hi * 4]);
                acc[4*g+0] = bv[0]; acc[4*g+1] = bv[1];
                acc[4*g+2] = bv[2]; acc[4*g+3] = bv[3];
            }
#pragma unroll
            for (int ks = 0; ks < 4; ++ks) {
                half8 kf = *reinterpret_cast<const half8*>(
                    curb + kb * 4096 + rbK + ((ks * 32 + hi * 16) ^ swK));
                acc = __builtin_amdgcn_mfma_f32_32x32x16_f16(kf, qf[ks], acc, 0, 0, 0);
            }
#pragma unroll
            for (int r = 0; r < 16; ++r) lsum += EXP2F(acc[r]);
        }
        __syncthreads();
        _Float16* t = cur; cur = nxt; nxt = t;
    }
    lsum += __shfl_xor(lsum, 32, 64);
    if (hi == 0)
        rsums_[(size_t)bh * 2048 + qt * 128 + wid * 32 + l31] = lsum;
}

// ---------------- kernel2: single pass, attn + O ----------------
__global__ __launch_bounds__(256, 2)
void attn_main(const float* __restrict__ qg_, const _Float16* __restrict__ kws_,
               const _Float16* __restrict__ vws_, const int* __restrict__ mg_,
               const float* __restrict__ rsums_,
               float* __restrict__ outg_, float* __restrict__ attng_)
{
    __shared__ _Float16 Kb[2][8192];
    __shared__ _Float16 Vb[2][8192];
    __shared__ _Float16 biasH[2048];
    __shared__ _Float16 Pb[4][32][40];      // per-wave P transpose buf (80B rows)
    const int tid = threadIdx.x, wid = tid >> 6, lane = tid & 63;
    const int l31 = lane & 31, hi = lane >> 5;
    const int bh = blockIdx.x & 31, qt = blockIdx.x >> 5;
    const int* mg = mg_ + (bh >> 4) * 2048;
    const _Float16* ktiles = kws_ + (size_t)bh * 16 * 8192;
    const _Float16* vtiles = vws_ + (size_t)bh * 16 * 8192;
    const int qrow_l = qt * 128 + wid * 32 + l31;

    const float* qrow = qg_ + ((size_t)bh * 2048 + qrow_l) * 64;
    half8 qf[4];
#pragma unroll
    for (int ks = 0; ks < 4; ++ks) {
        f32x4 x0 = *reinterpret_cast<const f32x4*>(qrow + ks * 16 + hi * 8);
        f32x4 x1 = *reinterpret_cast<const f32x4*>(qrow + ks * 16 + hi * 8 + 4);
#pragma unroll
        for (int j = 0; j < 4; ++j) {
            qf[ks][j]     = (_Float16)(x0[j] * QSCALE);
            qf[ks][4 + j] = (_Float16)(x1[j] * QSCALE);
        }
    }
#pragma unroll
    for (int i = 0; i < 2; ++i) {
        int j = (tid + 256 * i) * 4;
        i32x4 m = *reinterpret_cast<const i32x4*>(mg + j);
        half4v bv;
        bv[0] = m[0] ? (_Float16)NEGBIG : (_Float16)0.f;
        bv[1] = m[1] ? (_Float16)NEGBIG : (_Float16)0.f;
        bv[2] = m[2] ? (_Float16)NEGBIG : (_Float16)0.f;
        bv[3] = m[3] ? (_Float16)NEGBIG : (_Float16)0.f;
        *reinterpret_cast<half4v*>(&biasH[j]) = bv;
    }

    const float rs = rsums_[(size_t)bh * 2048 + qrow_l];
    const int   rm = mg[qrow_l];
    const bool uni = (rm != 0) || !(rs > 0.f);
    const float rscale = uni ? 0.f : 1.f / rs;
    const float radd   = uni ? (1.0f / 2048.0f) : 0.f;

    stage_tile16k(ktiles, Kb[0], wid, lane);
    stage_tile16k(vtiles, Vb[0], wid, lane);
    __syncthreads();

    f32x16 Oacc0, Oacc1;
#pragma unroll
    for (int r = 0; r < 16; ++r) { Oacc0[r] = 0.f; Oacc1[r] = 0.f; }

    // wave-level attn base (rows owned by this wave)
    float* attnw = attng_ + ((size_t)bh * 2048 + qt * 128 + wid * 32) * 2048;
    _Float16 *curK = Kb[0], *nxtK = Kb[1], *curV = Vb[0], *nxtV = Vb[1];

    const int rbK = (l31 >> 2) * 512 + (l31 & 3) * 128;
    const int swK = (l31 >> 2) << 4;
    const int rbV = (l31 >> 1) * 512 + (l31 & 1) * 256;
    const int swV = (l31 >> 1) << 4;

    for (int kc = 0; kc < 16; ++kc) {
        if (kc < 15) {
            stage_tile16k(ktiles + (size_t)(kc + 1) * 8192, nxtK, wid, lane);
            stage_tile16k(vtiles + (size_t)(kc + 1) * 8192, nxtV, wid, lane);
        }
        asm volatile("" ::: "memory");   // keep stage issues ahead of compute/stores
        const char* curKb = (const char*)curK;
        const char* curVb = (const char*)curV;
#pragma unroll
        for (int kb = 0; kb < 4; ++kb) {
            // S^T = K.Q (swapped): lane = q (l31), regs = k rows
            f32x16 acc;
#pragma unroll
            for (int g = 0; g < 4; ++g) {
                half4v bv = *reinterpret_cast<const half4v*>(
                    &biasH[kc * 128 + kb * 32 + g * 8 + hi * 4]);
                acc[4*g+0] = (float)bv[0]; acc[4*g+1] = (float)bv[1];
                acc[4*g+2] = (float)bv[2]; acc[4*g+3] = (float)bv[3];
            }
#pragma unroll
            for (int ks = 0; ks < 4; ++ks) {
                half8 kf = *reinterpret_cast<const half8*>(
                    curKb + kb * 4096 + rbK + ((ks * 32 + hi * 16) ^ swK));
                acc = __builtin_amdgcn_mfma_f32_32x32x16_f16(kf, qf[ks], acc, 0, 0, 0);
            }
            // normalized P; reg r holds k = (r&3)+8*(r>>2)+4*hi
            float p[16];
#pragma unroll
            for (int r = 0; r < 16; ++r) p[r] = EXP2F(acc[r]) * rscale + radd;

            // pack to f16 pairs (k-adjacent)
            u32 wA[4], wB[4];
#pragma unroll
            for (int t = 0; t < 4; ++t) {
                wA[t] = pkh(p[4*t],     p[4*t + 1]);
                wB[t] = pkh(p[4*t + 2], p[4*t + 3]);
            }
            // P -> wave-private LDS, [q=l31][k], for the store transpose
#pragma unroll
            for (int t = 0; t < 4; ++t) {
                u32x2 ww; ww[0] = wA[t]; ww[1] = wB[t];
                *reinterpret_cast<u32x2*>(&Pb[wid][l31][t * 8 + 4 * hi]) = ww;
            }
            asm volatile("s_waitcnt lgkmcnt(0)" ::: "memory");
            __builtin_amdgcn_sched_barrier(0);

            // readback transposed + coalesced nt stores (8 rows x 128B per instr)
#pragma unroll
            for (int i8 = 0; i8 < 4; ++i8) {
                int rl = i8 * 8 + (lane >> 3);
                half4v ph = *reinterpret_cast<half4v*>(&Pb[wid][rl][(lane & 7) * 4]);
                f32x4 pf;
                pf[0] = (float)ph[0]; pf[1] = (float)ph[1];
                pf[2] = (float)ph[2]; pf[3] = (float)ph[3];
                __builtin_nontemporal_store(pf, reinterpret_cast<f32x4*>(
                    attnw + (size_t)rl * 2048 + kc * 128 + kb * 32 + (lane & 7) * 4));
            }

            // T12: in-register P -> fp16 A-frags for PV
#pragma unroll
            for (int s = 0; s < 2; ++s) {
                u32 cA = wA[2*s], dA = wB[2*s], cB = wA[2*s + 1], dB = wB[2*s + 1];
                swap32(cA, cB);
                swap32(dA, dB);
                u32x4 wv; wv[0] = cA; wv[1] = dA; wv[2] = cB; wv[3] = dB;
                half8 af = __builtin_bit_cast(half8, wv);
#pragma unroll
                for (int nd = 0; nd < 2; ++nd) {
                    half8 bf = *reinterpret_cast<const half8*>(
                        curVb + nd * 8192 + rbV +
                        ((kb * 64 + s * 32 + hi * 16) ^ swV));
                    if (nd == 0) Oacc0 = __builtin_amdgcn_mfma_f32_32x32x16_f16(af, bf, Oacc0, 0, 0, 0);
                    else         Oacc1 = __builtin_amdgcn_mfma_f32_32x32x16_f16(af, bf, Oacc1, 0, 0, 0);
                }
            }
        }
        if (kc < 15) {
            // counted vmcnt: retire the 8 stage loads; chunk's 16 nt stores stay in flight
            asm volatile("s_waitcnt vmcnt(16) lgkmcnt(0)" ::: "memory");
            __builtin_amdgcn_s_barrier();
            _Float16* t;
            t = curK; curK = nxtK; nxtK = t;
            t = curV; curV = nxtV; nxtV = t;
        }
    }

    float* outg = outg_ + ((size_t)bh * 2048 + qt * 128) * 64;
#pragma unroll
    for (int r = 0; r < 16; ++r) {
        int q_l = wid * 32 + (r & 3) + 8 * (r >> 2) + 4 * hi;
        __builtin_nontemporal_store(Oacc0[r], outg + (size_t)q_l * 64 + l31);
        __builtin_nontemporal_store(Oacc1[r], outg + (size_t)q_l * 64 + 32 + l31);
    }
}

// ---------------- fallback: previous verified kernel (used if ws too small) ----------------
__global__ __launch_bounds__(256, 2)
void attn_fused(const float* __restrict__ qg_, const float* __restrict__ kg_,
                const float* __restrict__ vg_, const int* __restrict__ mg_,
                float* __restrict__ outg_, float* __restrict__ attng_)
{
    constexpr int N = 2048, D = 64, TM = 128, BK = 128, NCH = 16;
    constexpr int QS = 72, KS = 72, VTS = 136, PS = 72;
    constexpr float INVN = 1.0f / 2048.0f;

    __shared__ _Float16 Qs[TM * QS];
    __shared__ _Float16 Ksh[BK * KS];
    __shared__ _Float16 Vts[D * VTS];
    __shared__ _Float16 Ps[TM * PS];
    __shared__ unsigned char cm[N];

    const int tid  = threadIdx.x;
    const int wid  = tid >> 6;
    const int lane = tid & 63;
    const int quad = lane >> 4;
    const int l15  = lane & 15;

    const int bh = blockIdx.x & 31;
    const int qt = blockIdx.x >> 5;
    const int b  = bh >> 4;

    const float* qg = qg_ + ((size_t)bh * N + qt * TM) * D;
    const float* kg = kg_ + (size_t)bh * N * D;
    const float* vg = vg_ + (size_t)bh * N * D;
    const int*   mg = mg_ + (size_t)b * N;
    float* attng = attng_ + ((size_t)bh * N + (size_t)qt * TM) * N;
    float* outg  = outg_  + ((size_t)bh * N + qt * TM) * D;

#pragma unroll
    for (int i = 0; i < 8; ++i) {
        int f = tid + 256 * i;
        int row = f >> 4, d = (f & 15) * 4;
        float4 x = *reinterpret_cast<const float4*>(qg + (size_t)row * D + d);
        half4v hv;
        hv[0] = (_Float16)(x.x * QSCALE);
        hv[1] = (_Float16)(x.y * QSCALE);
        hv[2] = (_Float16)(x.z * QSCALE);
        hv[3] = (_Float16)(x.w * QSCALE);
        *reinterpret_cast<half4v*>(&Qs[row * QS + d]) = hv;
        cm[f] = (unsigned char)(mg[f] ? 0 : 1);
    }

    float rowm[2][4];
#pragma unroll
    for (int mb = 0; mb < 2; ++mb)
#pragma unroll
        for (int r = 0; r < 4; ++r) {
            int row = qt * TM + wid * 32 + mb * 16 + quad * 4 + r;
            rowm[mb][r] = (float)mg[row];
        }

    __syncthreads();

    half8 qfr[2][2];
#pragma unroll
    for (int mb = 0; mb < 2; ++mb)
#pragma unroll
        for (int ks = 0; ks < 2; ++ks)
            qfr[mb][ks] = *reinterpret_cast<half8*>(
                &Qs[(wid * 32 + mb * 16 + l15) * QS + ks * 32 + quad * 8]);

    float lsum[2][4] = {{0,0,0,0},{0,0,0,0}};

    for (int kc = 0; kc < NCH; ++kc) {
        __syncthreads();
#pragma unroll
        for (int i = 0; i < 8; ++i) {
            int f = tid + 256 * i;
            int row = f >> 4, d = (f & 15) * 4;
            float4 x = *reinterpret_cast<const float4*>(kg + (size_t)(kc * BK + row) * D + d);
            half4v hv;
            hv[0] = (_Float16)x.x; hv[1] = (_Float16)x.y;
            hv[2] = (_Float16)x.z; hv[3] = (_Float16)x.w;
            *reinterpret_cast<half4v*>(&Ksh[row * KS + d]) = hv;
        }
        __syncthreads();

#pragma unroll
        for (int mb = 0; mb < 2; ++mb) {
#pragma unroll
            for (int nb = 0; nb < 8; ++nb) {
                f32x4 acc = {0.f, 0.f, 0.f, 0.f};
#pragma unroll
                for (int ks = 0; ks < 2; ++ks) {
                    half8 bfr = *reinterpret_cast<half8*>(
                        &Ksh[(nb * 16 + l15) * KS + ks * 32 + quad * 8]);
                    acc = __builtin_amdgcn_mfma_f32_16x16x32_f16(qfr[mb][ks], bfr, acc, 0, 0, 0);
                }
                float cmf = (float)cm[kc * BK + nb * 16 + l15];
#pragma unroll
                for (int r = 0; r < 4; ++r)
                    lsum[mb][r] += cmf * EXP2F(acc[r]);
            }
        }
    }

#pragma unroll
    for (int mb = 0; mb < 2; ++mb)
#pragma unroll
        for (int r = 0; r < 4; ++r) {
            float s = lsum[mb][r];
            s += __shfl_xor(s, 1, 64);
            s += __shfl_xor(s, 2, 64);
            s += __shfl_xor(s, 4, 64);
            s += __shfl_xor(s, 8, 64);
            lsum[mb][r] = s;
        }

    float rscale[2][4], radd[2][4];
#pragma unroll
    for (int mb = 0; mb < 2; ++mb)
#pragma unroll
        for (int r = 0; r < 4; ++r) {
            bool uni = (rowm[mb][r] != 0.0f) || !(lsum[mb][r] > 0.0f);
            rscale[mb][r] = uni ? 0.0f : 1.0f / lsum[mb][r];
            radd[mb][r]   = uni ? INVN : 0.0f;
        }

    f32x4 Oacc[2][4];
#pragma unroll
    for (int mb = 0; mb < 2; ++mb)
#pragma unroll
        for (int nd = 0; nd < 4; ++nd)
            Oacc[mb][nd] = (f32x4){0.f, 0.f, 0.f, 0.f};

    for (int kc = 0; kc < NCH; ++kc) {
        __syncthreads();
#pragma unroll
        for (int i = 0; i < 8; ++i) {
            int f = tid + 256 * i;
            int row = f >> 4, d = (f & 15) * 4;
            float4 x = *reinterpret_cast<const float4*>(kg + (size_t)(kc * BK + row) * D + d);
            half4v hv;
            hv[0] = (_Float16)x.x; hv[1] = (_Float16)x.y;
            hv[2] = (_Float16)x.z; hv[3] = (_Float16)x.w;
            *reinterpret_cast<half4v*>(&Ksh[row * KS + d]) = hv;
        }
#pragma unroll
        for (int rr = 0; rr < 4; ++rr) {
            int key0 = rr * 32 + wid * 8;
            half8 hh;
#pragma unroll
            for (int j = 0; j < 8; ++j)
                hh[j] = (_Float16)vg[(size_t)(kc * BK + key0 + j) * D + lane];
            *reinterpret_cast<half8*>(&Vts[lane * VTS + key0]) = hh;
        }
        __syncthreads();

        f32x4 S[2][8];
#pragma unroll
        for (int mb = 0; mb < 2; ++mb)
#pragma unroll
            for (int nb = 0; nb < 8; ++nb) {
                f32x4 acc = {0.f, 0.f, 0.f, 0.f};
#pragma unroll
                for (int ks = 0; ks < 2; ++ks) {
                    half8 bfr = *reinterpret_cast<half8*>(
                        &Ksh[(nb * 16 + l15) * KS + ks * 32 + quad * 8]);
                    acc = __builtin_amdgcn_mfma_f32_16x16x32_f16(qfr[mb][ks], bfr, acc, 0, 0, 0);
                }
                S[mb][nb] = acc;
            }

#pragma unroll
        for (int h = 0; h < 2; ++h) {
#pragma unroll
            for (int nb2 = 0; nb2 < 4; ++nb2) {
                int nb = h * 4 + nb2;
                float cmf = (float)cm[kc * BK + nb * 16 + l15];
#pragma unroll
                for (int mb = 0; mb < 2; ++mb) {
#pragma unroll
                    for (int r = 0; r < 4; ++r) {
                        float p = cmf * EXP2F(S[mb][nb][r]) * rscale[mb][r] + radd[mb][r];
                        Ps[(wid * 32 + mb * 16 + quad * 4 + r) * PS + nb2 * 16 + l15] = (_Float16)p;
                    }
                }
            }
            asm volatile("s_waitcnt lgkmcnt(0)" ::: "memory");

#pragma unroll
            for (int r8 = 0; r8 < 8; ++r8) {
                int rl = r8 * 4 + quad;
                half4v ph = *reinterpret_cast<half4v*>(
                    &Ps[(wid * 32 + rl) * PS + l15 * 4]);
                f32x4 pf;
                pf[0] = (float)ph[0]; pf[1] = (float)ph[1];
                pf[2] = (float)ph[2]; pf[3] = (float)ph[3];
                float* dst = attng + (size_t)(wid * 32 + rl) * N + kc * BK + h * 64 + l15 * 4;
                __builtin_nontemporal_store(pf, reinterpret_cast<f32x4*>(dst));
            }

#pragma unroll
            for (int ks = 0; ks < 2; ++ks) {
                half8 af[2];
#pragma unroll
                for (int mb = 0; mb < 2; ++mb)
                    af[mb] = *reinterpret_cast<half8*>(
                        &Ps[(wid * 32 + mb * 16 + l15) * PS + ks * 32 + quad * 8]);
#pragma unroll
                for (int nd = 0; nd < 4; ++nd) {
                    half8 bfr = *reinterpret_cast<half8*>(
                        &Vts[(nd * 16 + l15) * VTS + h * 64 + ks * 32 + quad * 8]);
#pragma unroll
                    for (int mb = 0; mb < 2; ++mb)
                        Oacc[mb][nd] = __builtin_amdgcn_mfma_f32_16x16x32_f16(af[mb], bfr, Oacc[mb][nd], 0, 0, 0);
                }
            }
        }
    }

#pragma unroll
    for (int mb = 0; mb < 2; ++mb)
#pragma unroll
        for (int nd = 0; nd < 4; ++nd)
#pragma unroll
            for (int r = 0; r < 4; ++r)
                __builtin_nontemporal_store(
                    Oacc[mb][nd][r],
                    outg + (size_t)(wid * 32 + mb * 16 + quad * 4 + r) * D + nd * 16 + l15);
}

// ---------------- launch ----------------
extern "C" void kernel_launch(void* const* d_in, const int* in_sizes, int n_in,
                              void* d_out, int out_size, void* d_ws, size_t ws_size,
                              hipStream_t stream) {
    const float* q   = (const float*)d_in[0];
    const float* k   = (const float*)d_in[1];
    const float* v   = (const float*)d_in[2];
    const int*   msk = (const int*)d_in[3];
    float* out  = (float*)d_out;
    float* attn = out + (size_t)2 * 16 * 2048 * 64;   // output first, then attn

    const size_t kv_halves = (size_t)32 * 2048 * 64;          // per tensor
    const size_t need = kv_halves * 2 * sizeof(_Float16)      // Kws + Vws
                      + (size_t)32 * 2048 * sizeof(float);    // row sums
    if (d_ws != nullptr && ws_size >= need) {
        _Float16* kws = (_Float16*)d_ws;
        _Float16* vws = kws + kv_halves;
        float* rsums  = (float*)(vws + kv_halves);
        hipLaunchKernelGGL(prep_kv,   dim3(512), dim3(256), 0, stream, k, v, kws, vws);
        hipLaunchKernelGGL(attn_sums, dim3(512), dim3(256), 0, stream, q, kws, msk, rsums);
        hipLaunchKernelGGL(attn_main, dim3(512), dim3(256), 0, stream,
                           q, kws, vws, msk, rsums, out, attn);
    } else {
        hipLaunchKernelGGL(attn_fused, dim3(512), dim3(256), 0, stream,
                           q, k, v, msk, out, attn);
    }
}

// Round 3
// 656.135 us; speedup vs baseline: 1.8882x; 1.0502x over previous
//
#include <hip/hip_runtime.h>

typedef _Float16 half8 __attribute__((ext_vector_type(8)));
typedef _Float16 half4v __attribute__((ext_vector_type(4)));
typedef _Float16 half2v __attribute__((ext_vector_type(2)));
typedef float f32x4 __attribute__((ext_vector_type(4)));
typedef float f32x16 __attribute__((ext_vector_type(16)));
typedef unsigned int u32;
typedef u32 u32x2 __attribute__((ext_vector_type(2)));
typedef u32 u32x4 __attribute__((ext_vector_type(4)));
typedef int i32x4 __attribute__((ext_vector_type(4)));

#if __has_builtin(__builtin_amdgcn_exp2f)
#define EXP2F(x) __builtin_amdgcn_exp2f(x)
#else
#define EXP2F(x) exp2f(x)
#endif

// fold 1/TEMPERATURE and log2(e) into Q so scores are exp2-ready
#define QSCALE (1.44269504088896340736f * 0.125f)
// column-mask bias folded into MFMA C-init: exp2(s + NEGBIG) == 0 exactly
#define NEGBIG (-16384.0f)

// ---------------- helpers ----------------

__device__ __forceinline__ void gload_lds16(const void* g, void* l) {
    __builtin_amdgcn_global_load_lds(
        (const __attribute__((address_space(1))) u32*)g,
        (__attribute__((address_space(3))) u32*)l, 16, 0, 0);
}

// stage one 16KB tile: 4 waves x 4 issues x 64 lanes x 16B (linear, async)
__device__ __forceinline__ void stage_tile16k(const _Float16* g, _Float16* l,
                                              int wid, int lane) {
#pragma unroll
    for (int i = 0; i < 4; ++i) {
        const int base = (wid * 4 + i) * 1024;
        gload_lds16((const char*)g + base + lane * 16, (char*)l + base);
    }
}

__device__ __forceinline__ u32 pkh(float a, float b) {   // RTE f32x2 -> f16x2
    half2v h; h[0] = (_Float16)a; h[1] = (_Float16)b;
    return __builtin_bit_cast(u32, h);
}

// v_permlane32_swap_b32: rows 32-63 of first operand <-> rows 0-31 of second.
__device__ __forceinline__ void swap32(u32 &a, u32 &b) {
    asm volatile("v_permlane32_swap_b32 %0, %1" : "+v"(a), "+v"(b));
}

// ---- conflict-free tile layouts (pre-permuted in global by prep_kv) ----
// K tile 16KB: k-row r (0..127), byte c (0..127):
//   L = (r>>2)*512 + (r&3)*128 + (c ^ (((r>>2)&7)<<4))
// V tile 16KB: d-row d (0..63), byte c (0..255):
//   L = (d>>1)*512 + (d&1)*256 + (c ^ (((d>>1)&15)<<4))

// ---------------- kernel0: K,V -> fp16 workspace tiles ----------------
__global__ __launch_bounds__(256, 2)
void prep_kv(const float* __restrict__ kg_, const float* __restrict__ vg_,
             _Float16* __restrict__ kws_, _Float16* __restrict__ vws_)
{
    __shared__ float tile[128 * 68];
    const int tid = threadIdx.x;
    const int bh  = blockIdx.x & 31;
    const int kc  = blockIdx.x >> 5;
    const float* kg = kg_ + ((size_t)bh * 2048 + kc * 128) * 64;
    const float* vg = vg_ + ((size_t)bh * 2048 + kc * 128) * 64;
    _Float16* kt = kws_ + ((size_t)bh * 16 + kc) * 8192;
    _Float16* vt = vws_ + ((size_t)bh * 16 + kc) * 8192;

    // ---- K ----
#pragma unroll
    for (int i = 0; i < 8; ++i) {
        int f = tid + 256 * i;                 // 2048 float4s
        int r = f >> 4, c4 = f & 15;
        f32x4 x = *reinterpret_cast<const f32x4*>(kg + r * 64 + c4 * 4);
        *reinterpret_cast<f32x4*>(&tile[r * 68 + c4 * 4]) = x;
    }
    __syncthreads();
#pragma unroll
    for (int i = 0; i < 4; ++i) {
        int s16 = tid + 256 * i;               // 16B unit, [0,1024)
        int R5 = s16 >> 5;                     // r>>2
        int r  = R5 * 4 + ((s16 >> 3) & 3);
        int c  = ((s16 & 7) << 4) ^ ((R5 & 7) << 4);
        int d0 = c >> 1;                       // half index, multiple of 8
        f32x4 x0 = *reinterpret_cast<const f32x4*>(&tile[r * 68 + d0]);
        f32x4 x1 = *reinterpret_cast<const f32x4*>(&tile[r * 68 + d0 + 4]);
        half8 h;
#pragma unroll
        for (int j = 0; j < 4; ++j) { h[j] = (_Float16)x0[j]; h[4 + j] = (_Float16)x1[j]; }
        __builtin_nontemporal_store(h, reinterpret_cast<half8*>(kt + s16 * 8));
    }
    __syncthreads();
    // ---- V (transposed) ----
#pragma unroll
    for (int i = 0; i < 8; ++i) {
        int f = tid + 256 * i;
        int r = f >> 4, c4 = f & 15;
        f32x4 x = *reinterpret_cast<const f32x4*>(vg + r * 64 + c4 * 4);
        *reinterpret_cast<f32x4*>(&tile[r * 68 + c4 * 4]) = x;
    }
    __syncthreads();
#pragma unroll
    for (int i = 0; i < 4; ++i) {
        int s16 = tid + 256 * i;
        int R5 = s16 >> 5;                     // d>>1
        int d  = R5 * 2 + ((s16 >> 4) & 1);
        int c  = ((s16 & 15) << 4) ^ ((R5 & 15) << 4);
        int k0 = c >> 1;                       // key index, multiple of 8
        half8 h;
#pragma unroll
        for (int j = 0; j < 8; ++j) h[j] = (_Float16)tile[(k0 + j) * 68 + d];
        __builtin_nontemporal_store(h, reinterpret_cast<half8*>(vt + s16 * 8));
    }
}

// ---------------- fused attention: phase1 sums + phase2 attn/O ----------------
__global__ __launch_bounds__(256, 2)
void attn_ws(const float* __restrict__ qg_, const _Float16* __restrict__ kws_,
             const _Float16* __restrict__ vws_, const int* __restrict__ mg_,
             float* __restrict__ outg_, float* __restrict__ attng_)
{
    __shared__ _Float16 Kb[2][8192];        // 32 KB (double-buffered K chunk)
    __shared__ _Float16 Vb[2][8192];        // 32 KB
    __shared__ _Float16 biasH[2048];        // 4 KB column-mask bias
    __shared__ _Float16 Pb[4][32][36];      // 9 KB per-wave P transpose buf (72B rows)
    const int tid = threadIdx.x, wid = tid >> 6, lane = tid & 63;
    const int l31 = lane & 31, hi = lane >> 5;
    const int bh = blockIdx.x & 31, qt = blockIdx.x >> 5;
    const int* mg = mg_ + (bh >> 4) * 2048;
    const _Float16* ktiles = kws_ + (size_t)bh * 16 * 8192;
    const _Float16* vtiles = vws_ + (size_t)bh * 16 * 8192;
    const int qrow_l = qt * 128 + wid * 32 + l31;

    // Q fragments (registers for whole kernel)
    const float* qrow = qg_ + ((size_t)bh * 2048 + qrow_l) * 64;
    half8 qf[4];
#pragma unroll
    for (int ks = 0; ks < 4; ++ks) {
        f32x4 x0 = *reinterpret_cast<const f32x4*>(qrow + ks * 16 + hi * 8);
        f32x4 x1 = *reinterpret_cast<const f32x4*>(qrow + ks * 16 + hi * 8 + 4);
#pragma unroll
        for (int j = 0; j < 4; ++j) {
            qf[ks][j]     = (_Float16)(x0[j] * QSCALE);
            qf[ks][4 + j] = (_Float16)(x1[j] * QSCALE);
        }
    }
    // column bias (f16: -16384 exact)
#pragma unroll
    for (int i = 0; i < 2; ++i) {
        int j = (tid + 256 * i) * 4;
        i32x4 m = *reinterpret_cast<const i32x4*>(mg + j);
        half4v bv;
        bv[0] = m[0] ? (_Float16)NEGBIG : (_Float16)0.f;
        bv[1] = m[1] ? (_Float16)NEGBIG : (_Float16)0.f;
        bv[2] = m[2] ? (_Float16)NEGBIG : (_Float16)0.f;
        bv[3] = m[3] ? (_Float16)NEGBIG : (_Float16)0.f;
        *reinterpret_cast<half4v*>(&biasH[j]) = bv;
    }

    stage_tile16k(ktiles, Kb[0], wid, lane);
    __syncthreads();

    const int rbK = (l31 >> 2) * 512 + (l31 & 3) * 128;
    const int swK = (l31 >> 2) << 4;
    const int rbV = (l31 >> 1) * 512 + (l31 & 1) * 256;
    const int swV = (l31 >> 1) << 4;

    // ================= PHASE 1: row sums of exp2(masked scores) =================
    float lsum = 0.f;
    for (int kc = 0; kc < 16; ++kc) {
        if (kc < 15)
            stage_tile16k(ktiles + (size_t)(kc + 1) * 8192, Kb[(kc + 1) & 1], wid, lane);
        asm volatile("" ::: "memory");
        const char* curb = (const char*)Kb[kc & 1];
#pragma unroll
        for (int kb = 0; kb < 4; ++kb) {
            f32x16 acc;
#pragma unroll
            for (int g = 0; g < 4; ++g) {
                half4v bv = *reinterpret_cast<const half4v*>(
                    &biasH[kc * 128 + kb * 32 + g * 8 + hi * 4]);
                acc[4*g+0] = (float)bv[0]; acc[4*g+1] = (float)bv[1];
                acc[4*g+2] = (float)bv[2]; acc[4*g+3] = (float)bv[3];
            }
#pragma unroll
            for (int ks = 0; ks < 4; ++ks) {
                half8 kf = *reinterpret_cast<const half8*>(
                    curb + kb * 4096 + rbK + ((ks * 32 + hi * 16) ^ swK));
                acc = __builtin_amdgcn_mfma_f32_32x32x16_f16(kf, qf[ks], acc, 0, 0, 0);
            }
#pragma unroll
            for (int r = 0; r < 16; ++r) lsum += EXP2F(acc[r]);
        }
        if (kc < 15) {
            asm volatile("s_waitcnt vmcnt(0) lgkmcnt(0)" ::: "memory");
            __builtin_amdgcn_s_barrier();
        }
    }

    // K15 is still resident in Kb[1]; stage V15 now, do softmax math under the load
    stage_tile16k(vtiles + (size_t)15 * 8192, Vb[1], wid, lane);

    lsum += __shfl_xor(lsum, 32, 64);
    const int  rm  = mg[qrow_l];
    const bool uni = (rm != 0) || !(lsum > 0.f);
    const float rscale = uni ? 0.f : 1.f / lsum;
    const float radd   = uni ? (1.0f / 2048.0f) : 0.f;

    f32x16 Oacc0, Oacc1;
#pragma unroll
    for (int r = 0; r < 16; ++r) { Oacc0[r] = 0.f; Oacc1[r] = 0.f; }

    asm volatile("s_waitcnt vmcnt(0) lgkmcnt(0)" ::: "memory");
    __builtin_amdgcn_s_barrier();

    // ================= PHASE 2 (reverse chunks): attn store + O accumulate =========
    float* attnw = attng_ + ((size_t)bh * 2048 + qt * 128 + wid * 32) * 2048;
    for (int kc = 15; kc >= 0; --kc) {
        if (kc > 0) {
            stage_tile16k(ktiles + (size_t)(kc - 1) * 8192, Kb[(kc - 1) & 1], wid, lane);
            stage_tile16k(vtiles + (size_t)(kc - 1) * 8192, Vb[(kc - 1) & 1], wid, lane);
        }
        asm volatile("" ::: "memory");   // keep stage issues ahead of compute/stores
        const char* curKb = (const char*)Kb[kc & 1];
        const char* curVb = (const char*)Vb[kc & 1];
#pragma unroll
        for (int kb = 0; kb < 4; ++kb) {
            // S^T = K.Q (swapped): lane = q (l31), regs = k rows
            f32x16 acc;
#pragma unroll
            for (int g = 0; g < 4; ++g) {
                half4v bv = *reinterpret_cast<const half4v*>(
                    &biasH[kc * 128 + kb * 32 + g * 8 + hi * 4]);
                acc[4*g+0] = (float)bv[0]; acc[4*g+1] = (float)bv[1];
                acc[4*g+2] = (float)bv[2]; acc[4*g+3] = (float)bv[3];
            }
#pragma unroll
            for (int ks = 0; ks < 4; ++ks) {
                half8 kf = *reinterpret_cast<const half8*>(
                    curKb + kb * 4096 + rbK + ((ks * 32 + hi * 16) ^ swK));
                acc = __builtin_amdgcn_mfma_f32_32x32x16_f16(kf, qf[ks], acc, 0, 0, 0);
            }
            // normalized P; reg r holds k = (r&3)+8*(r>>2)+4*hi
            float p[16];
#pragma unroll
            for (int r = 0; r < 16; ++r) p[r] = EXP2F(acc[r]) * rscale + radd;

            // pack to f16 pairs (k-adjacent)
            u32 wA[4], wB[4];
#pragma unroll
            for (int t = 0; t < 4; ++t) {
                wA[t] = pkh(p[4*t],     p[4*t + 1]);
                wB[t] = pkh(p[4*t + 2], p[4*t + 3]);
            }
            // P -> wave-private LDS [q=l31][k] for the store transpose (in-order DS pipe)
#pragma unroll
            for (int t = 0; t < 4; ++t) {
                u32x2 ww; ww[0] = wA[t]; ww[1] = wB[t];
                *reinterpret_cast<u32x2*>(&Pb[wid][l31][t * 8 + 4 * hi]) = ww;
            }

            // PV first — depends only on registers, NOT on the LDS round-trip
#pragma unroll
            for (int s = 0; s < 2; ++s) {
                u32 cA = wA[2*s], dA = wB[2*s], cB = wA[2*s + 1], dB = wB[2*s + 1];
                swap32(cA, cB);
                swap32(dA, dB);
                u32x4 wv; wv[0] = cA; wv[1] = dA; wv[2] = cB; wv[3] = dB;
                half8 af = __builtin_bit_cast(half8, wv);
#pragma unroll
                for (int nd = 0; nd < 2; ++nd) {
                    half8 bf = *reinterpret_cast<const half8*>(
                        curVb + nd * 8192 + rbV +
                        ((kb * 64 + s * 32 + hi * 16) ^ swV));
                    if (nd == 0) Oacc0 = __builtin_amdgcn_mfma_f32_32x32x16_f16(af, bf, Oacc0, 0, 0, 0);
                    else         Oacc1 = __builtin_amdgcn_mfma_f32_32x32x16_f16(af, bf, Oacc1, 0, 0, 0);
                }
            }

            // drain DS (P writes long since retired under PV), then transpose-readback
            asm volatile("s_waitcnt lgkmcnt(0)" ::: "memory");
#pragma unroll
            for (int i8 = 0; i8 < 4; ++i8) {
                int rl = i8 * 8 + (lane >> 3);
                half4v ph = *reinterpret_cast<half4v*>(&Pb[wid][rl][(lane & 7) * 4]);
                f32x4 pf;
                pf[0] = (float)ph[0]; pf[1] = (float)ph[1];
                pf[2] = (float)ph[2]; pf[3] = (float)ph[3];
                __builtin_nontemporal_store(pf, reinterpret_cast<f32x4*>(
                    attnw + (size_t)rl * 2048 + kc * 128 + kb * 32 + (lane & 7) * 4));
            }
        }
        if (kc > 0) {
            // counted vmcnt: retire the 8 stage loads; this chunk's nt stores stay in flight
            asm volatile("s_waitcnt vmcnt(16) lgkmcnt(0)" ::: "memory");
            __builtin_amdgcn_s_barrier();
        }
    }

    float* outg = outg_ + ((size_t)bh * 2048 + qt * 128) * 64;
#pragma unroll
    for (int r = 0; r < 16; ++r) {
        int q_l = wid * 32 + (r & 3) + 8 * (r >> 2) + 4 * hi;
        __builtin_nontemporal_store(Oacc0[r], outg + (size_t)q_l * 64 + l31);
        __builtin_nontemporal_store(Oacc1[r], outg + (size_t)q_l * 64 + 32 + l31);
    }
}

// ---------------- fallback: previous verified kernel (used if ws too small) ----------------
__global__ __launch_bounds__(256, 2)
void attn_fused(const float* __restrict__ qg_, const float* __restrict__ kg_,
                const float* __restrict__ vg_, const int* __restrict__ mg_,
                float* __restrict__ outg_, float* __restrict__ attng_)
{
    constexpr int N = 2048, D = 64, TM = 128, BK = 128, NCH = 16;
    constexpr int QS = 72, KS = 72, VTS = 136, PS = 72;
    constexpr float INVN = 1.0f / 2048.0f;

    __shared__ _Float16 Qs[TM * QS];
    __shared__ _Float16 Ksh[BK * KS];
    __shared__ _Float16 Vts[D * VTS];
    __shared__ _Float16 Ps[TM * PS];
    __shared__ unsigned char cm[N];

    const int tid  = threadIdx.x;
    const int wid  = tid >> 6;
    const int lane = tid & 63;
    const int quad = lane >> 4;
    const int l15  = lane & 15;

    const int bh = blockIdx.x & 31;
    const int qt = blockIdx.x >> 5;
    const int b  = bh >> 4;

    const float* qg = qg_ + ((size_t)bh * N + qt * TM) * D;
    const float* kg = kg_ + (size_t)bh * N * D;
    const float* vg = vg_ + (size_t)bh * N * D;
    const int*   mg = mg_ + (size_t)b * N;
    float* attng = attng_ + ((size_t)bh * N + (size_t)qt * TM) * N;
    float* outg  = outg_  + ((size_t)bh * N + qt * TM) * D;

#pragma unroll
    for (int i = 0; i < 8; ++i) {
        int f = tid + 256 * i;
        int row = f >> 4, d = (f & 15) * 4;
        float4 x = *reinterpret_cast<const float4*>(qg + (size_t)row * D + d);
        half4v hv;
        hv[0] = (_Float16)(x.x * QSCALE);
        hv[1] = (_Float16)(x.y * QSCALE);
        hv[2] = (_Float16)(x.z * QSCALE);
        hv[3] = (_Float16)(x.w * QSCALE);
        *reinterpret_cast<half4v*>(&Qs[row * QS + d]) = hv;
        cm[f] = (unsigned char)(mg[f] ? 0 : 1);
    }

    float rowm[2][4];
#pragma unroll
    for (int mb = 0; mb < 2; ++mb)
#pragma unroll
        for (int r = 0; r < 4; ++r) {
            int row = qt * TM + wid * 32 + mb * 16 + quad * 4 + r;
            rowm[mb][r] = (float)mg[row];
        }

    __syncthreads();

    half8 qfr[2][2];
#pragma unroll
    for (int mb = 0; mb < 2; ++mb)
#pragma unroll
        for (int ks = 0; ks < 2; ++ks)
            qfr[mb][ks] = *reinterpret_cast<half8*>(
                &Qs[(wid * 32 + mb * 16 + l15) * QS + ks * 32 + quad * 8]);

    float lsum[2][4] = {{0,0,0,0},{0,0,0,0}};

    for (int kc = 0; kc < NCH; ++kc) {
        __syncthreads();
#pragma unroll
        for (int i = 0; i < 8; ++i) {
            int f = tid + 256 * i;
            int row = f >> 4, d = (f & 15) * 4;
            float4 x = *reinterpret_cast<const float4*>(kg + (size_t)(kc * BK + row) * D + d);
            half4v hv;
            hv[0] = (_Float16)x.x; hv[1] = (_Float16)x.y;
            hv[2] = (_Float16)x.z; hv[3] = (_Float16)x.w;
            *reinterpret_cast<half4v*>(&Ksh[row * KS + d]) = hv;
        }
        __syncthreads();

#pragma unroll
        for (int mb = 0; mb < 2; ++mb) {
#pragma unroll
            for (int nb = 0; nb < 8; ++nb) {
                f32x4 acc = {0.f, 0.f, 0.f, 0.f};
#pragma unroll
                for (int ks = 0; ks < 2; ++ks) {
                    half8 bfr = *reinterpret_cast<half8*>(
                        &Ksh[(nb * 16 + l15) * KS + ks * 32 + quad * 8]);
                    acc = __builtin_amdgcn_mfma_f32_16x16x32_f16(qfr[mb][ks], bfr, acc, 0, 0, 0);
                }
                float cmf = (float)cm[kc * BK + nb * 16 + l15];
#pragma unroll
                for (int r = 0; r < 4; ++r)
                    lsum[mb][r] += cmf * EXP2F(acc[r]);
            }
        }
    }

#pragma unroll
    for (int mb = 0; mb < 2; ++mb)
#pragma unroll
        for (int r = 0; r < 4; ++r) {
            float s = lsum[mb][r];
            s += __shfl_xor(s, 1, 64);
            s += __shfl_xor(s, 2, 64);
            s += __shfl_xor(s, 4, 64);
            s += __shfl_xor(s, 8, 64);
            lsum[mb][r] = s;
        }

    float rscale[2][4], radd[2][4];
#pragma unroll
    for (int mb = 0; mb < 2; ++mb)
#pragma unroll
        for (int r = 0; r < 4; ++r) {
            bool uni = (rowm[mb][r] != 0.0f) || !(lsum[mb][r] > 0.0f);
            rscale[mb][r] = uni ? 0.0f : 1.0f / lsum[mb][r];
            radd[mb][r]   = uni ? INVN : 0.0f;
        }

    f32x4 Oacc[2][4];
#pragma unroll
    for (int mb = 0; mb < 2; ++mb)
#pragma unroll
        for (int nd = 0; nd < 4; ++nd)
            Oacc[mb][nd] = (f32x4){0.f, 0.f, 0.f, 0.f};

    for (int kc = 0; kc < NCH; ++kc) {
        __syncthreads();
#pragma unroll
        for (int i = 0; i < 8; ++i) {
            int f = tid + 256 * i;
            int row = f >> 4, d = (f & 15) * 4;
            float4 x = *reinterpret_cast<const float4*>(kg + (size_t)(kc * BK + row) * D + d);
            half4v hv;
            hv[0] = (_Float16)x.x; hv[1] = (_Float16)x.y;
            hv[2] = (_Float16)x.z; hv[3] = (_Float16)x.w;
            *reinterpret_cast<half4v*>(&Ksh[row * KS + d]) = hv;
        }
#pragma unroll
        for (int rr = 0; rr < 4; ++rr) {
            int key0 = rr * 32 + wid * 8;
            half8 hh;
#pragma unroll
            for (int j = 0; j < 8; ++j)
                hh[j] = (_Float16)vg[(size_t)(kc * BK + key0 + j) * D + lane];
            *reinterpret_cast<half8*>(&Vts[lane * VTS + key0]) = hh;
        }
        __syncthreads();

        f32x4 S[2][8];
#pragma unroll
        for (int mb = 0; mb < 2; ++mb)
#pragma unroll
            for (int nb = 0; nb < 8; ++nb) {
                f32x4 acc = {0.f, 0.f, 0.f, 0.f};
#pragma unroll
                for (int ks = 0; ks < 2; ++ks) {
                    half8 bfr = *reinterpret_cast<half8*>(
                        &Ksh[(nb * 16 + l15) * KS + ks * 32 + quad * 8]);
                    acc = __builtin_amdgcn_mfma_f32_16x16x32_f16(qfr[mb][ks], bfr, acc, 0, 0, 0);
                }
                S[mb][nb] = acc;
            }

#pragma unroll
        for (int h = 0; h < 2; ++h) {
#pragma unroll
            for (int nb2 = 0; nb2 < 4; ++nb2) {
                int nb = h * 4 + nb2;
                float cmf = (float)cm[kc * BK + nb * 16 + l15];
#pragma unroll
                for (int mb = 0; mb < 2; ++mb) {
#pragma unroll
                    for (int r = 0; r < 4; ++r) {
                        float p = cmf * EXP2F(S[mb][nb][r]) * rscale[mb][r] + radd[mb][r];
                        Ps[(wid * 32 + mb * 16 + quad * 4 + r) * PS + nb2 * 16 + l15] = (_Float16)p;
                    }
                }
            }
            asm volatile("s_waitcnt lgkmcnt(0)" ::: "memory");

#pragma unroll
            for (int r8 = 0; r8 < 8; ++r8) {
                int rl = r8 * 4 + quad;
                half4v ph = *reinterpret_cast<half4v*>(
                    &Ps[(wid * 32 + rl) * PS + l15 * 4]);
                f32x4 pf;
                pf[0] = (float)ph[0]; pf[1] = (float)ph[1];
                pf[2] = (float)ph[2]; pf[3] = (float)ph[3];
                float* dst = attng + (size_t)(wid * 32 + rl) * N + kc * BK + h * 64 + l15 * 4;
                __builtin_nontemporal_store(pf, reinterpret_cast<f32x4*>(dst));
            }

#pragma unroll
            for (int ks = 0; ks < 2; ++ks) {
                half8 af[2];
#pragma unroll
                for (int mb = 0; mb < 2; ++mb)
                    af[mb] = *reinterpret_cast<half8*>(
                        &Ps[(wid * 32 + mb * 16 + l15) * PS + ks * 32 + quad * 8]);
#pragma unroll
                for (int nd = 0; nd < 4; ++nd) {
                    half8 bfr = *reinterpret_cast<half8*>(
                        &Vts[(nd * 16 + l15) * VTS + h * 64 + ks * 32 + quad * 8]);
#pragma unroll
                    for (int mb = 0; mb < 2; ++mb)
                        Oacc[mb][nd] = __builtin_amdgcn_mfma_f32_16x16x32_f16(af[mb], bfr, Oacc[mb][nd], 0, 0, 0);
                }
            }
        }
    }

#pragma unroll
    for (int mb = 0; mb < 2; ++mb)
#pragma unroll
        for (int nd = 0; nd < 4; ++nd)
#pragma unroll
            for (int r = 0; r < 4; ++r)
                __builtin_nontemporal_store(
                    Oacc[mb][nd][r],
                    outg + (size_t)(wid * 32 + mb * 16 + quad * 4 + r) * D + nd * 16 + l15);
}

// ---------------- launch ----------------
extern "C" void kernel_launch(void* const* d_in, const int* in_sizes, int n_in,
                              void* d_out, int out_size, void* d_ws, size_t ws_size,
                              hipStream_t stream) {
    const float* q   = (const float*)d_in[0];
    const float* k   = (const float*)d_in[1];
    const float* v   = (const float*)d_in[2];
    const int*   msk = (const int*)d_in[3];
    float* out  = (float*)d_out;
    float* attn = out + (size_t)2 * 16 * 2048 * 64;   // output first, then attn

    const size_t kv_halves = (size_t)32 * 2048 * 64;          // per tensor
    const size_t need = kv_halves * 2 * sizeof(_Float16);     // Kws + Vws
    if (d_ws != nullptr && ws_size >= need) {
        _Float16* kws = (_Float16*)d_ws;
        _Float16* vws = kws + kv_halves;
        hipLaunchKernelGGL(prep_kv, dim3(512), dim3(256), 0, stream, k, v, kws, vws);
        hipLaunchKernelGGL(attn_ws, dim3(512), dim3(256), 0, stream,
                           q, kws, vws, msk, out, attn);
    } else {
        hipLaunchKernelGGL(attn_fused, dim3(512), dim3(256), 0, stream,
                           q, k, v, msk, out, attn);
    }
}

// Round 4
// 653.682 us; speedup vs baseline: 1.8953x; 1.0038x over previous
//
#include <hip/hip_runtime.h>

typedef _Float16 half8 __attribute__((ext_vector_type(8)));
typedef _Float16 half4v __attribute__((ext_vector_type(4)));
typedef _Float16 half2v __attribute__((ext_vector_type(2)));
typedef float f32x4 __attribute__((ext_vector_type(4)));
typedef float f32x16 __attribute__((ext_vector_type(16)));
typedef unsigned int u32;
typedef u32 u32x2 __attribute__((ext_vector_type(2)));
typedef u32 u32x4 __attribute__((ext_vector_type(4)));
typedef int i32x4 __attribute__((ext_vector_type(4)));

#if __has_builtin(__builtin_amdgcn_exp2f)
#define EXP2F(x) __builtin_amdgcn_exp2f(x)
#else
#define EXP2F(x) exp2f(x)
#endif

// fold 1/TEMPERATURE and log2(e) into Q so scores are exp2-ready
#define QSCALE (1.44269504088896340736f * 0.125f)
// column-mask bias folded into MFMA C-init: exp2(s + NEGBIG) == 0 exactly
#define NEGBIG (-16384.0f)

// ---------------- helpers ----------------

__device__ __forceinline__ void gload_lds16(const void* g, void* l) {
    __builtin_amdgcn_global_load_lds(
        (const __attribute__((address_space(1))) u32*)g,
        (__attribute__((address_space(3))) u32*)l, 16, 0, 0);
}

// stage one 16KB tile: 4 waves x 4 issues x 64 lanes x 16B (linear, async)
__device__ __forceinline__ void stage_tile16k(const _Float16* g, _Float16* l,
                                              int wid, int lane) {
#pragma unroll
    for (int i = 0; i < 4; ++i) {
        const int base = (wid * 4 + i) * 1024;
        gload_lds16((const char*)g + base + lane * 16, (char*)l + base);
    }
}

__device__ __forceinline__ u32 pkh(float a, float b) {   // RTE f32x2 -> f16x2
    half2v h; h[0] = (_Float16)a; h[1] = (_Float16)b;
    return __builtin_bit_cast(u32, h);
}

// v_permlane32_swap_b32: rows 32-63 of first operand <-> rows 0-31 of second.
__device__ __forceinline__ void swap32(u32 &a, u32 &b) {
    asm volatile("v_permlane32_swap_b32 %0, %1" : "+v"(a), "+v"(b));
}

// ---- conflict-free tile layouts (pre-permuted in global by prep_kv) ----
// K tile 16KB: k-row r (0..127), byte c (0..127):
//   L = (r>>2)*512 + (r&3)*128 + (c ^ (((r>>2)&7)<<4))
// V tile 16KB: d-row d (0..63), byte c (0..255):
//   L = (d>>1)*512 + (d&1)*256 + (c ^ (((d>>1)&15)<<4))

// ---------------- kernel0: K,V -> fp16 workspace tiles ----------------
__global__ __launch_bounds__(256, 2)
void prep_kv(const float* __restrict__ kg_, const float* __restrict__ vg_,
             _Float16* __restrict__ kws_, _Float16* __restrict__ vws_)
{
    __shared__ float tile[128 * 68];
    const int tid = threadIdx.x;
    const int bh  = blockIdx.x & 31;
    const int kc  = blockIdx.x >> 5;
    const float* kg = kg_ + ((size_t)bh * 2048 + kc * 128) * 64;
    const float* vg = vg_ + ((size_t)bh * 2048 + kc * 128) * 64;
    _Float16* kt = kws_ + ((size_t)bh * 16 + kc) * 8192;
    _Float16* vt = vws_ + ((size_t)bh * 16 + kc) * 8192;

    // ---- K ----
#pragma unroll
    for (int i = 0; i < 8; ++i) {
        int f = tid + 256 * i;                 // 2048 float4s
        int r = f >> 4, c4 = f & 15;
        f32x4 x = *reinterpret_cast<const f32x4*>(kg + r * 64 + c4 * 4);
        *reinterpret_cast<f32x4*>(&tile[r * 68 + c4 * 4]) = x;
    }
    __syncthreads();
#pragma unroll
    for (int i = 0; i < 4; ++i) {
        int s16 = tid + 256 * i;               // 16B unit, [0,1024)
        int R5 = s16 >> 5;                     // r>>2
        int r  = R5 * 4 + ((s16 >> 3) & 3);
        int c  = ((s16 & 7) << 4) ^ ((R5 & 7) << 4);
        int d0 = c >> 1;                       // half index, multiple of 8
        f32x4 x0 = *reinterpret_cast<const f32x4*>(&tile[r * 68 + d0]);
        f32x4 x1 = *reinterpret_cast<const f32x4*>(&tile[r * 68 + d0 + 4]);
        half8 h;
#pragma unroll
        for (int j = 0; j < 4; ++j) { h[j] = (_Float16)x0[j]; h[4 + j] = (_Float16)x1[j]; }
        __builtin_nontemporal_store(h, reinterpret_cast<half8*>(kt + s16 * 8));
    }
    __syncthreads();
    // ---- V (transposed) ----
#pragma unroll
    for (int i = 0; i < 8; ++i) {
        int f = tid + 256 * i;
        int r = f >> 4, c4 = f & 15;
        f32x4 x = *reinterpret_cast<const f32x4*>(vg + r * 64 + c4 * 4);
        *reinterpret_cast<f32x4*>(&tile[r * 68 + c4 * 4]) = x;
    }
    __syncthreads();
#pragma unroll
    for (int i = 0; i < 4; ++i) {
        int s16 = tid + 256 * i;
        int R5 = s16 >> 5;                     // d>>1
        int d  = R5 * 2 + ((s16 >> 4) & 1);
        int c  = ((s16 & 15) << 4) ^ ((R5 & 15) << 4);
        int k0 = c >> 1;                       // key index, multiple of 8
        half8 h;
#pragma unroll
        for (int j = 0; j < 8; ++j) h[j] = (_Float16)tile[(k0 + j) * 68 + d];
        __builtin_nontemporal_store(h, reinterpret_cast<half8*>(vt + s16 * 8));
    }
}

// ---------------- kernel1: partial row sums over a k-half (grid 1024, 4 blk/CU) ---
__global__ __launch_bounds__(256, 4)
void attn_sums2(const float* __restrict__ qg_, const _Float16* __restrict__ kws_,
                const int* __restrict__ mg_, float* __restrict__ rsums_)
{
    __shared__ _Float16 Kb[2][8192];
    __shared__ _Float16 biasH[2048];
    const int tid = threadIdx.x, wid = tid >> 6, lane = tid & 63;
    const int l31 = lane & 31, hi = lane >> 5;
    const int bh = blockIdx.x & 31;
    const int kh = (blockIdx.x >> 5) & 1;
    const int qt = blockIdx.x >> 6;
    const int* mg = mg_ + (bh >> 4) * 2048;
    const _Float16* ktiles = kws_ + (size_t)bh * 16 * 8192;

    const float* qrow = qg_ + ((size_t)bh * 2048 + qt * 128 + wid * 32 + l31) * 64;
    half8 qf[4];
#pragma unroll
    for (int ks = 0; ks < 4; ++ks) {
        f32x4 x0 = *reinterpret_cast<const f32x4*>(qrow + ks * 16 + hi * 8);
        f32x4 x1 = *reinterpret_cast<const f32x4*>(qrow + ks * 16 + hi * 8 + 4);
#pragma unroll
        for (int j = 0; j < 4; ++j) {
            qf[ks][j]     = (_Float16)(x0[j] * QSCALE);
            qf[ks][4 + j] = (_Float16)(x1[j] * QSCALE);
        }
    }
#pragma unroll
    for (int i = 0; i < 2; ++i) {
        int j = (tid + 256 * i) * 4;
        i32x4 m = *reinterpret_cast<const i32x4*>(mg + j);
        half4v bv;
        bv[0] = m[0] ? (_Float16)NEGBIG : (_Float16)0.f;
        bv[1] = m[1] ? (_Float16)NEGBIG : (_Float16)0.f;
        bv[2] = m[2] ? (_Float16)NEGBIG : (_Float16)0.f;
        bv[3] = m[3] ? (_Float16)NEGBIG : (_Float16)0.f;
        *reinterpret_cast<half4v*>(&biasH[j]) = bv;
    }
    stage_tile16k(ktiles + (size_t)(kh * 8) * 8192, Kb[0], wid, lane);
    __syncthreads();

    const int rbK = (l31 >> 2) * 512 + (l31 & 3) * 128;
    const int swK = (l31 >> 2) << 4;

    float lsum = 0.f;
    for (int ic = 0; ic < 8; ++ic) {
        const int kc = kh * 8 + ic;
        if (ic < 7)
            stage_tile16k(ktiles + (size_t)(kc + 1) * 8192, Kb[(ic + 1) & 1], wid, lane);
        asm volatile("" ::: "memory");
        const char* curb = (const char*)Kb[ic & 1];
#pragma unroll
        for (int kb = 0; kb < 4; ++kb) {
            f32x16 acc;
#pragma unroll
            for (int g = 0; g < 4; ++g) {
                half4v bv = *reinterpret_cast<const half4v*>(
                    &biasH[kc * 128 + kb * 32 + g * 8 + hi * 4]);
                acc[4*g+0] = (float)bv[0]; acc[4*g+1] = (float)bv[1];
                acc[4*g+2] = (float)bv[2]; acc[4*g+3] = (float)bv[3];
            }
#pragma unroll
            for (int ks = 0; ks < 4; ++ks) {
                half8 kf = *reinterpret_cast<const half8*>(
                    curb + kb * 4096 + rbK + ((ks * 32 + hi * 16) ^ swK));
                acc = __builtin_amdgcn_mfma_f32_32x32x16_f16(kf, qf[ks], acc, 0, 0, 0);
            }
#pragma unroll
            for (int r = 0; r < 16; ++r) lsum += EXP2F(acc[r]);
        }
        if (ic < 7) {
            asm volatile("s_waitcnt vmcnt(0) lgkmcnt(0)" ::: "memory");
            __builtin_amdgcn_s_barrier();
        }
    }
    lsum += __shfl_xor(lsum, 32, 64);
    if (hi == 0)
        unsafeAtomicAdd(&rsums_[(size_t)bh * 2048 + qt * 128 + wid * 32 + l31], lsum);
}

// ------- kernel2: attn store + O accumulate over a k-half (grid 1024, 3 blk/CU) ----
__global__ __launch_bounds__(256, 3)
void attn_main2(const float* __restrict__ qg_, const _Float16* __restrict__ kws_,
                const _Float16* __restrict__ vws_, const int* __restrict__ mg_,
                const float* __restrict__ rsums_,
                float* __restrict__ outg_, float* __restrict__ attng_)
{
    __shared__ _Float16 Kb[2][8192];        // 32 KB (double-buffered K chunk)
    __shared__ _Float16 biasH[2048];        // 4 KB column-mask bias
    __shared__ _Float16 Pb[4][32][68];      // 17 KB per-wave 2-kb P transpose buf
    // total 53 KB -> 3 blocks/CU
    const int tid = threadIdx.x, wid = tid >> 6, lane = tid & 63;
    const int l31 = lane & 31, hi = lane >> 5;
    const int bh = blockIdx.x & 31;         // same bh -> same XCD (L2 locality)
    const int kh = (blockIdx.x >> 5) & 1;
    const int qt = blockIdx.x >> 6;
    const int* mg = mg_ + (bh >> 4) * 2048;
    const _Float16* ktiles = kws_ + (size_t)bh * 16 * 8192;
    const _Float16* vtiles = vws_ + (size_t)bh * 16 * 8192;
    const int qrow_l = qt * 128 + wid * 32 + l31;

    const float* qrow = qg_ + ((size_t)bh * 2048 + qrow_l) * 64;
    half8 qf[4];
#pragma unroll
    for (int ks = 0; ks < 4; ++ks) {
        f32x4 x0 = *reinterpret_cast<const f32x4*>(qrow + ks * 16 + hi * 8);
        f32x4 x1 = *reinterpret_cast<const f32x4*>(qrow + ks * 16 + hi * 8 + 4);
#pragma unroll
        for (int j = 0; j < 4; ++j) {
            qf[ks][j]     = (_Float16)(x0[j] * QSCALE);
            qf[ks][4 + j] = (_Float16)(x1[j] * QSCALE);
        }
    }
#pragma unroll
    for (int i = 0; i < 2; ++i) {
        int j = (tid + 256 * i) * 4;
        i32x4 m = *reinterpret_cast<const i32x4*>(mg + j);
        half4v bv;
        bv[0] = m[0] ? (_Float16)NEGBIG : (_Float16)0.f;
        bv[1] = m[1] ? (_Float16)NEGBIG : (_Float16)0.f;
        bv[2] = m[2] ? (_Float16)NEGBIG : (_Float16)0.f;
        bv[3] = m[3] ? (_Float16)NEGBIG : (_Float16)0.f;
        *reinterpret_cast<half4v*>(&biasH[j]) = bv;
    }

    const float rs = rsums_[(size_t)bh * 2048 + qrow_l];
    const int   rm = mg[qrow_l];
    const bool uni = (rm != 0) || !(rs > 0.f);
    const float rscale = uni ? 0.f : 1.f / rs;
    const float radd   = uni ? (1.0f / 2048.0f) : 0.f;

    stage_tile16k(ktiles + (size_t)(kh * 8) * 8192, Kb[0], wid, lane);
    __syncthreads();

    f32x16 Oacc0, Oacc1;
#pragma unroll
    for (int r = 0; r < 16; ++r) { Oacc0[r] = 0.f; Oacc1[r] = 0.f; }

    float* attnw = attng_ + ((size_t)bh * 2048 + qt * 128 + wid * 32) * 2048;

    const int rbK = (l31 >> 2) * 512 + (l31 & 3) * 128;
    const int swK = (l31 >> 2) << 4;
    const int rbV = (l31 >> 1) * 512 + (l31 & 1) * 256;
    const int swV = (l31 >> 1) << 4;

    for (int ic = 0; ic < 8; ++ic) {
        const int kc = kh * 8 + ic;
        if (ic < 7)
            stage_tile16k(ktiles + (size_t)(kc + 1) * 8192, Kb[(ic + 1) & 1], wid, lane);
        asm volatile("" ::: "memory");   // keep stage issues ahead of compute/stores
        const char* curKb = (const char*)Kb[ic & 1];
        const char* vchunk = (const char*)vtiles + (size_t)kc * 16384;
#pragma unroll
        for (int kb = 0; kb < 4; ++kb) {
            // V fragments straight from L2-resident workspace (per-wave regs);
            // issued before QK so ~1 kb of MFMA+exp2 hides the L2 latency
            half8 vf[4];
#pragma unroll
            for (int s = 0; s < 2; ++s)
#pragma unroll
                for (int nd = 0; nd < 2; ++nd)
                    vf[s * 2 + nd] = *reinterpret_cast<const half8*>(
                        vchunk + nd * 8192 + rbV +
                        ((kb * 64 + s * 32 + hi * 16) ^ swV));

            // S^T = K.Q (swapped): lane = q (l31), regs = k rows
            f32x16 acc;
#pragma unroll
            for (int g = 0; g < 4; ++g) {
                half4v bv = *reinterpret_cast<const half4v*>(
                    &biasH[kc * 128 + kb * 32 + g * 8 + hi * 4]);
                acc[4*g+0] = (float)bv[0]; acc[4*g+1] = (float)bv[1];
                acc[4*g+2] = (float)bv[2]; acc[4*g+3] = (float)bv[3];
            }
#pragma unroll
            for (int ks = 0; ks < 4; ++ks) {
                half8 kf = *reinterpret_cast<const half8*>(
                    curKb + kb * 4096 + rbK + ((ks * 32 + hi * 16) ^ swK));
                acc = __builtin_amdgcn_mfma_f32_32x32x16_f16(kf, qf[ks], acc, 0, 0, 0);
            }
            // normalized P; reg r holds k = (r&3)+8*(r>>2)+4*hi
            float p[16];
#pragma unroll
            for (int r = 0; r < 16; ++r) p[r] = EXP2F(acc[r]) * rscale + radd;

            u32 wA[4], wB[4];
#pragma unroll
            for (int t = 0; t < 4; ++t) {
                wA[t] = pkh(p[4*t],     p[4*t + 1]);
                wB[t] = pkh(p[4*t + 2], p[4*t + 3]);
            }
            // P -> wave-private LDS [q=l31][2-kb cols] for the store transpose
#pragma unroll
            for (int t = 0; t < 4; ++t) {
                u32x2 ww; ww[0] = wA[t]; ww[1] = wB[t];
                *reinterpret_cast<u32x2*>(&Pb[wid][l31][(kb & 1) * 32 + t * 8 + 4 * hi]) = ww;
            }

            // PV (registers only; V from vf)
#pragma unroll
            for (int s = 0; s < 2; ++s) {
                u32 cA = wA[2*s], dA = wB[2*s], cB = wA[2*s + 1], dB = wB[2*s + 1];
                swap32(cA, cB);
                swap32(dA, dB);
                u32x4 wv; wv[0] = cA; wv[1] = dA; wv[2] = cB; wv[3] = dB;
                half8 af = __builtin_bit_cast(half8, wv);
                if (s == 0) {
                    Oacc0 = __builtin_amdgcn_mfma_f32_32x32x16_f16(af, vf[0], Oacc0, 0, 0, 0);
                    Oacc1 = __builtin_amdgcn_mfma_f32_32x32x16_f16(af, vf[1], Oacc1, 0, 0, 0);
                } else {
                    Oacc0 = __builtin_amdgcn_mfma_f32_32x32x16_f16(af, vf[2], Oacc0, 0, 0, 0);
                    Oacc1 = __builtin_amdgcn_mfma_f32_32x32x16_f16(af, vf[3], Oacc1, 0, 0, 0);
                }
            }

            // every 2 kb: transpose-readback + 256B-segment nt stores (4 rows x 256B)
            if (kb & 1) {
                asm volatile("s_waitcnt lgkmcnt(0)" ::: "memory");
#pragma unroll
                for (int i8 = 0; i8 < 8; ++i8) {
                    int rl = i8 * 4 + (lane >> 4);
                    half4v ph = *reinterpret_cast<half4v*>(&Pb[wid][rl][(lane & 15) * 4]);
                    f32x4 pf;
                    pf[0] = (float)ph[0]; pf[1] = (float)ph[1];
                    pf[2] = (float)ph[2]; pf[3] = (float)ph[3];
                    __builtin_nontemporal_store(pf, reinterpret_cast<f32x4*>(
                        attnw + (size_t)rl * 2048 + kc * 128 + (kb >> 1) * 64 + (lane & 15) * 4));
                }
            }
        }
        if (ic < 7) {
            // counted vmcnt: retire the 4 stage loads; this chunk's 16 nt stores stay in flight
            asm volatile("s_waitcnt vmcnt(16) lgkmcnt(0)" ::: "memory");
            __builtin_amdgcn_s_barrier();
        }
    }

    // O partial for this k-half: accumulate into zeroed out buffer (2 commutative adds)
    float* outg = outg_ + ((size_t)bh * 2048 + qt * 128) * 64;
#pragma unroll
    for (int r = 0; r < 16; ++r) {
        int q_l = wid * 32 + (r & 3) + 8 * (r >> 2) + 4 * hi;
        unsafeAtomicAdd(outg + (size_t)q_l * 64 + l31, Oacc0[r]);
        unsafeAtomicAdd(outg + (size_t)q_l * 64 + 32 + l31, Oacc1[r]);
    }
}

// ---------------- fallback: previous verified kernel (used if ws too small) ----------------
__global__ __launch_bounds__(256, 2)
void attn_fused(const float* __restrict__ qg_, const float* __restrict__ kg_,
                const float* __restrict__ vg_, const int* __restrict__ mg_,
                float* __restrict__ outg_, float* __restrict__ attng_)
{
    constexpr int N = 2048, D = 64, TM = 128, BK = 128, NCH = 16;
    constexpr int QS = 72, KS = 72, VTS = 136, PS = 72;
    constexpr float INVN = 1.0f / 2048.0f;

    __shared__ _Float16 Qs[TM * QS];
    __shared__ _Float16 Ksh[BK * KS];
    __shared__ _Float16 Vts[D * VTS];
    __shared__ _Float16 Ps[TM * PS];
    __shared__ unsigned char cm[N];

    const int tid  = threadIdx.x;
    const int wid  = tid >> 6;
    const int lane = tid & 63;
    const int quad = lane >> 4;
    const int l15  = lane & 15;

    const int bh = blockIdx.x & 31;
    const int qt = blockIdx.x >> 5;
    const int b  = bh >> 4;

    const float* qg = qg_ + ((size_t)bh * N + qt * TM) * D;
    const float* kg = kg_ + (size_t)bh * N * D;
    const float* vg = vg_ + (size_t)bh * N * D;
    const int*   mg = mg_ + (size_t)b * N;
    float* attng = attng_ + ((size_t)bh * N + (size_t)qt * TM) * N;
    float* outg  = outg_  + ((size_t)bh * N + qt * TM) * D;

#pragma unroll
    for (int i = 0; i < 8; ++i) {
        int f = tid + 256 * i;
        int row = f >> 4, d = (f & 15) * 4;
        float4 x = *reinterpret_cast<const float4*>(qg + (size_t)row * D + d);
        half4v hv;
        hv[0] = (_Float16)(x.x * QSCALE);
        hv[1] = (_Float16)(x.y * QSCALE);
        hv[2] = (_Float16)(x.z * QSCALE);
        hv[3] = (_Float16)(x.w * QSCALE);
        *reinterpret_cast<half4v*>(&Qs[row * QS + d]) = hv;
        cm[f] = (unsigned char)(mg[f] ? 0 : 1);
    }

    float rowm[2][4];
#pragma unroll
    for (int mb = 0; mb < 2; ++mb)
#pragma unroll
        for (int r = 0; r < 4; ++r) {
            int row = qt * TM + wid * 32 + mb * 16 + quad * 4 + r;
            rowm[mb][r] = (float)mg[row];
        }

    __syncthreads();

    half8 qfr[2][2];
#pragma unroll
    for (int mb = 0; mb < 2; ++mb)
#pragma unroll
        for (int ks = 0; ks < 2; ++ks)
            qfr[mb][ks] = *reinterpret_cast<half8*>(
                &Qs[(wid * 32 + mb * 16 + l15) * QS + ks * 32 + quad * 8]);

    float lsum[2][4] = {{0,0,0,0},{0,0,0,0}};

    for (int kc = 0; kc < NCH; ++kc) {
        __syncthreads();
#pragma unroll
        for (int i = 0; i < 8; ++i) {
            int f = tid + 256 * i;
            int row = f >> 4, d = (f & 15) * 4;
            float4 x = *reinterpret_cast<const float4*>(kg + (size_t)(kc * BK + row) * D + d);
            half4v hv;
            hv[0] = (_Float16)x.x; hv[1] = (_Float16)x.y;
            hv[2] = (_Float16)x.z; hv[3] = (_Float16)x.w;
            *reinterpret_cast<half4v*>(&Ksh[row * KS + d]) = hv;
        }
        __syncthreads();

#pragma unroll
        for (int mb = 0; mb < 2; ++mb) {
#pragma unroll
            for (int nb = 0; nb < 8; ++nb) {
                f32x4 acc = {0.f, 0.f, 0.f, 0.f};
#pragma unroll
                for (int ks = 0; ks < 2; ++ks) {
                    half8 bfr = *reinterpret_cast<half8*>(
                        &Ksh[(nb * 16 + l15) * KS + ks * 32 + quad * 8]);
                    acc = __builtin_amdgcn_mfma_f32_16x16x32_f16(qfr[mb][ks], bfr, acc, 0, 0, 0);
                }
                float cmf = (float)cm[kc * BK + nb * 16 + l15];
#pragma unroll
                for (int r = 0; r < 4; ++r)
                    lsum[mb][r] += cmf * EXP2F(acc[r]);
            }
        }
    }

#pragma unroll
    for (int mb = 0; mb < 2; ++mb)
#pragma unroll
        for (int r = 0; r < 4; ++r) {
            float s = lsum[mb][r];
            s += __shfl_xor(s, 1, 64);
            s += __shfl_xor(s, 2, 64);
            s += __shfl_xor(s, 4, 64);
            s += __shfl_xor(s, 8, 64);
            lsum[mb][r] = s;
        }

    float rscale[2][4], radd[2][4];
#pragma unroll
    for (int mb = 0; mb < 2; ++mb)
#pragma unroll
        for (int r = 0; r < 4; ++r) {
            bool uni = (rowm[mb][r] != 0.0f) || !(lsum[mb][r] > 0.0f);
            rscale[mb][r] = uni ? 0.0f : 1.0f / lsum[mb][r];
            radd[mb][r]   = uni ? INVN : 0.0f;
        }

    f32x4 Oacc[2][4];
#pragma unroll
    for (int mb = 0; mb < 2; ++mb)
#pragma unroll
        for (int nd = 0; nd < 4; ++nd)
            Oacc[mb][nd] = (f32x4){0.f, 0.f, 0.f, 0.f};

    for (int kc = 0; kc < NCH; ++kc) {
        __syncthreads();
#pragma unroll
        for (int i = 0; i < 8; ++i) {
            int f = tid + 256 * i;
            int row = f >> 4, d = (f & 15) * 4;
            float4 x = *reinterpret_cast<const float4*>(kg + (size_t)(kc * BK + row) * D + d);
            half4v hv;
            hv[0] = (_Float16)x.x; hv[1] = (_Float16)x.y;
            hv[2] = (_Float16)x.z; hv[3] = (_Float16)x.w;
            *reinterpret_cast<half4v*>(&Ksh[row * KS + d]) = hv;
        }
#pragma unroll
        for (int rr = 0; rr < 4; ++rr) {
            int key0 = rr * 32 + wid * 8;
            half8 hh;
#pragma unroll
            for (int j = 0; j < 8; ++j)
                hh[j] = (_Float16)vg[(size_t)(kc * BK + key0 + j) * D + lane];
            *reinterpret_cast<half8*>(&Vts[lane * VTS + key0]) = hh;
        }
        __syncthreads();

        f32x4 S[2][8];
#pragma unroll
        for (int mb = 0; mb < 2; ++mb)
#pragma unroll
            for (int nb = 0; nb < 8; ++nb) {
                f32x4 acc = {0.f, 0.f, 0.f, 0.f};
#pragma unroll
                for (int ks = 0; ks < 2; ++ks) {
                    half8 bfr = *reinterpret_cast<half8*>(
                        &Ksh[(nb * 16 + l15) * KS + ks * 32 + quad * 8]);
                    acc = __builtin_amdgcn_mfma_f32_16x16x32_f16(qfr[mb][ks], bfr, acc, 0, 0, 0);
                }
                S[mb][nb] = acc;
            }

#pragma unroll
        for (int h = 0; h < 2; ++h) {
#pragma unroll
            for (int nb2 = 0; nb2 < 4; ++nb2) {
                int nb = h * 4 + nb2;
                float cmf = (float)cm[kc * BK + nb * 16 + l15];
#pragma unroll
                for (int mb = 0; mb < 2; ++mb) {
#pragma unroll
                    for (int r = 0; r < 4; ++r) {
                        float p = cmf * EXP2F(S[mb][nb][r]) * rscale[mb][r] + radd[mb][r];
                        Ps[(wid * 32 + mb * 16 + quad * 4 + r) * PS + nb2 * 16 + l15] = (_Float16)p;
                    }
                }
            }
            asm volatile("s_waitcnt lgkmcnt(0)" ::: "memory");

#pragma unroll
            for (int r8 = 0; r8 < 8; ++r8) {
                int rl = r8 * 4 + quad;
                half4v ph = *reinterpret_cast<half4v*>(
                    &Ps[(wid * 32 + rl) * PS + l15 * 4]);
                f32x4 pf;
                pf[0] = (float)ph[0]; pf[1] = (float)ph[1];
                pf[2] = (float)ph[2]; pf[3] = (float)ph[3];
                float* dst = attng + (size_t)(wid * 32 + rl) * N + kc * BK + h * 64 + l15 * 4;
                __builtin_nontemporal_store(pf, reinterpret_cast<f32x4*>(dst));
            }

#pragma unroll
            for (int ks = 0; ks < 2; ++ks) {
                half8 af[2];
#pragma unroll
                for (int mb = 0; mb < 2; ++mb)
                    af[mb] = *reinterpret_cast<half8*>(
                        &Ps[(wid * 32 + mb * 16 + l15) * PS + ks * 32 + quad * 8]);
#pragma unroll
                for (int nd = 0; nd < 4; ++nd) {
                    half8 bfr = *reinterpret_cast<half8*>(
                        &Vts[(nd * 16 + l15) * VTS + h * 64 + ks * 32 + quad * 8]);
#pragma unroll
                    for (int mb = 0; mb < 2; ++mb)
                        Oacc[mb][nd] = __builtin_amdgcn_mfma_f32_16x16x32_f16(af[mb], bfr, Oacc[mb][nd], 0, 0, 0);
                }
            }
        }
    }

#pragma unroll
    for (int mb = 0; mb < 2; ++mb)
#pragma unroll
        for (int nd = 0; nd < 4; ++nd)
#pragma unroll
            for (int r = 0; r < 4; ++r)
                __builtin_nontemporal_store(
                    Oacc[mb][nd][r],
                    outg + (size_t)(wid * 32 + mb * 16 + quad * 4 + r) * D + nd * 16 + l15);
}

// ---------------- launch ----------------
extern "C" void kernel_launch(void* const* d_in, const int* in_sizes, int n_in,
                              void* d_out, int out_size, void* d_ws, size_t ws_size,
                              hipStream_t stream) {
    const float* q   = (const float*)d_in[0];
    const float* k   = (const float*)d_in[1];
    const float* v   = (const float*)d_in[2];
    const int*   msk = (const int*)d_in[3];
    float* out  = (float*)d_out;
    float* attn = out + (size_t)2 * 16 * 2048 * 64;   // output first, then attn

    const size_t kv_halves = (size_t)32 * 2048 * 64;          // per tensor
    const size_t rsum_bytes = (size_t)32 * 2048 * sizeof(float);
    const size_t need = kv_halves * 2 * sizeof(_Float16) + rsum_bytes;
    if (d_ws != nullptr && ws_size >= need) {
        _Float16* kws = (_Float16*)d_ws;
        _Float16* vws = kws + kv_halves;
        float* rsums  = (float*)(vws + kv_halves);
        hipMemsetAsync(rsums, 0, rsum_bytes, stream);
        hipMemsetAsync(out, 0, (size_t)2 * 16 * 2048 * 64 * sizeof(float), stream);
        hipLaunchKernelGGL(prep_kv,    dim3(512),  dim3(256), 0, stream, k, v, kws, vws);
        hipLaunchKernelGGL(attn_sums2, dim3(1024), dim3(256), 0, stream, q, kws, msk, rsums);
        hipLaunchKernelGGL(attn_main2, dim3(1024), dim3(256), 0, stream,
                           q, kws, vws, msk, rsums, out, attn);
    } else {
        hipLaunchKernelGGL(attn_fused, dim3(512), dim3(256), 0, stream,
                           q, k, v, msk, out, attn);
    }
}

// Round 5
// 643.541 us; speedup vs baseline: 1.9251x; 1.0158x over previous
//
#include <hip/hip_runtime.h>

typedef _Float16 half8 __attribute__((ext_vector_type(8)));
typedef _Float16 half4v __attribute__((ext_vector_type(4)));
typedef _Float16 half2v __attribute__((ext_vector_type(2)));
typedef float f32x4 __attribute__((ext_vector_type(4)));
typedef float f32x16 __attribute__((ext_vector_type(16)));
typedef unsigned int u32;
typedef u32 u32x2 __attribute__((ext_vector_type(2)));
typedef u32 u32x4 __attribute__((ext_vector_type(4)));
typedef int i32x4 __attribute__((ext_vector_type(4)));

#if __has_builtin(__builtin_amdgcn_exp2f)
#define EXP2F(x) __builtin_amdgcn_exp2f(x)
#else
#define EXP2F(x) exp2f(x)
#endif

// fold 1/TEMPERATURE and log2(e) into Q so scores are exp2-ready
#define QSCALE (1.44269504088896340736f * 0.125f)
// column-mask bias folded into MFMA C-init: exp2(s + NEGBIG) == 0 exactly
#define NEGBIG (-16384.0f)

// ---------------- helpers ----------------

__device__ __forceinline__ void gload_lds16(const void* g, void* l) {
    __builtin_amdgcn_global_load_lds(
        (const __attribute__((address_space(1))) u32*)g,
        (__attribute__((address_space(3))) u32*)l, 16, 0, 0);
}

// stage one 16KB tile: 4 waves x 4 issues x 64 lanes x 16B (linear, async)
__device__ __forceinline__ void stage_tile16k(const _Float16* g, _Float16* l,
                                              int wid, int lane) {
#pragma unroll
    for (int i = 0; i < 4; ++i) {
        const int base = (wid * 4 + i) * 1024;
        gload_lds16((const char*)g + base + lane * 16, (char*)l + base);
    }
}

__device__ __forceinline__ u32 pkh(float a, float b) {   // RTE f32x2 -> f16x2
    half2v h; h[0] = (_Float16)a; h[1] = (_Float16)b;
    return __builtin_bit_cast(u32, h);
}

// v_permlane32_swap_b32: rows 32-63 of first operand <-> rows 0-31 of second.
__device__ __forceinline__ void swap32(u32 &a, u32 &b) {
    asm volatile("v_permlane32_swap_b32 %0, %1" : "+v"(a), "+v"(b));
}

// ---- conflict-free tile layouts (pre-permuted in global by prep_kv) ----
// K tile 16KB: k-row r (0..127), byte c (0..127):
//   L = (r>>2)*512 + (r&3)*128 + (c ^ (((r>>2)&7)<<4))
// V tile 16KB: d-row d (0..63), byte c (0..255):
//   L = (d>>1)*512 + (d&1)*256 + (c ^ (((d>>1)&15)<<4))

// ---------------- kernel0: K,V -> fp16 workspace tiles ----------------
__global__ __launch_bounds__(256, 2)
void prep_kv(const float* __restrict__ kg_, const float* __restrict__ vg_,
             _Float16* __restrict__ kws_, _Float16* __restrict__ vws_)
{
    __shared__ float tile[128 * 68];
    const int tid = threadIdx.x;
    const int bh  = blockIdx.x & 31;
    const int kc  = blockIdx.x >> 5;
    const float* kg = kg_ + ((size_t)bh * 2048 + kc * 128) * 64;
    const float* vg = vg_ + ((size_t)bh * 2048 + kc * 128) * 64;
    _Float16* kt = kws_ + ((size_t)bh * 16 + kc) * 8192;
    _Float16* vt = vws_ + ((size_t)bh * 16 + kc) * 8192;

    // ---- K ----
#pragma unroll
    for (int i = 0; i < 8; ++i) {
        int f = tid + 256 * i;                 // 2048 float4s
        int r = f >> 4, c4 = f & 15;
        f32x4 x = *reinterpret_cast<const f32x4*>(kg + r * 64 + c4 * 4);
        *reinterpret_cast<f32x4*>(&tile[r * 68 + c4 * 4]) = x;
    }
    __syncthreads();
#pragma unroll
    for (int i = 0; i < 4; ++i) {
        int s16 = tid + 256 * i;               // 16B unit, [0,1024)
        int R5 = s16 >> 5;                     // r>>2
        int r  = R5 * 4 + ((s16 >> 3) & 3);
        int c  = ((s16 & 7) << 4) ^ ((R5 & 7) << 4);
        int d0 = c >> 1;                       // half index, multiple of 8
        f32x4 x0 = *reinterpret_cast<const f32x4*>(&tile[r * 68 + d0]);
        f32x4 x1 = *reinterpret_cast<const f32x4*>(&tile[r * 68 + d0 + 4]);
        half8 h;
#pragma unroll
        for (int j = 0; j < 4; ++j) { h[j] = (_Float16)x0[j]; h[4 + j] = (_Float16)x1[j]; }
        __builtin_nontemporal_store(h, reinterpret_cast<half8*>(kt + s16 * 8));
    }
    __syncthreads();
    // ---- V (transposed) ----
#pragma unroll
    for (int i = 0; i < 8; ++i) {
        int f = tid + 256 * i;
        int r = f >> 4, c4 = f & 15;
        f32x4 x = *reinterpret_cast<const f32x4*>(vg + r * 64 + c4 * 4);
        *reinterpret_cast<f32x4*>(&tile[r * 68 + c4 * 4]) = x;
    }
    __syncthreads();
#pragma unroll
    for (int i = 0; i < 4; ++i) {
        int s16 = tid + 256 * i;
        int R5 = s16 >> 5;                     // d>>1
        int d  = R5 * 2 + ((s16 >> 4) & 1);
        int c  = ((s16 & 15) << 4) ^ ((R5 & 15) << 4);
        int k0 = c >> 1;                       // key index, multiple of 8
        half8 h;
#pragma unroll
        for (int j = 0; j < 8; ++j) h[j] = (_Float16)tile[(k0 + j) * 68 + d];
        __builtin_nontemporal_store(h, reinterpret_cast<half8*>(vt + s16 * 8));
    }
}

// ---------------- fused attention: phase1 sums + phase2 attn/O ----------------
__global__ __launch_bounds__(256, 2)
void attn_ws(const float* __restrict__ qg_, const _Float16* __restrict__ kws_,
             const _Float16* __restrict__ vws_, const int* __restrict__ mg_,
             float* __restrict__ outg_, float* __restrict__ attng_)
{
    __shared__ _Float16 Kb[2][8192];        // 32 KB (double-buffered K chunk)
    __shared__ _Float16 Vb[2][8192];        // 32 KB
    __shared__ _Float16 biasH[2048];        // 4 KB column-mask bias
    __shared__ _Float16 Pb[4][32][36];      // 9 KB per-wave P transpose buf (72B rows)
    const int tid = threadIdx.x, wid = tid >> 6, lane = tid & 63;
    const int l31 = lane & 31, hi = lane >> 5;
    const int bh = blockIdx.x & 31, qt = blockIdx.x >> 5;
    const int* mg = mg_ + (bh >> 4) * 2048;
    const _Float16* ktiles = kws_ + (size_t)bh * 16 * 8192;
    const _Float16* vtiles = vws_ + (size_t)bh * 16 * 8192;
    const int qrow_l = qt * 128 + wid * 32 + l31;

    // Q fragments (registers for whole kernel)
    const float* qrow = qg_ + ((size_t)bh * 2048 + qrow_l) * 64;
    half8 qf[4];
#pragma unroll
    for (int ks = 0; ks < 4; ++ks) {
        f32x4 x0 = *reinterpret_cast<const f32x4*>(qrow + ks * 16 + hi * 8);
        f32x4 x1 = *reinterpret_cast<const f32x4*>(qrow + ks * 16 + hi * 8 + 4);
#pragma unroll
        for (int j = 0; j < 4; ++j) {
            qf[ks][j]     = (_Float16)(x0[j] * QSCALE);
            qf[ks][4 + j] = (_Float16)(x1[j] * QSCALE);
        }
    }
    // column bias (f16: -16384 exact)
#pragma unroll
    for (int i = 0; i < 2; ++i) {
        int j = (tid + 256 * i) * 4;
        i32x4 m = *reinterpret_cast<const i32x4*>(mg + j);
        half4v bv;
        bv[0] = m[0] ? (_Float16)NEGBIG : (_Float16)0.f;
        bv[1] = m[1] ? (_Float16)NEGBIG : (_Float16)0.f;
        bv[2] = m[2] ? (_Float16)NEGBIG : (_Float16)0.f;
        bv[3] = m[3] ? (_Float16)NEGBIG : (_Float16)0.f;
        *reinterpret_cast<half4v*>(&biasH[j]) = bv;
    }

    stage_tile16k(ktiles, Kb[0], wid, lane);
    __syncthreads();

    const int rbK = (l31 >> 2) * 512 + (l31 & 3) * 128;
    const int swK = (l31 >> 2) << 4;
    const int rbV = (l31 >> 1) * 512 + (l31 & 1) * 256;
    const int swV = (l31 >> 1) << 4;

    // ================= PHASE 1: row sums of exp2(masked scores) =================
    float lsum = 0.f;
    for (int kc = 0; kc < 16; ++kc) {
        if (kc < 15)
            stage_tile16k(ktiles + (size_t)(kc + 1) * 8192, Kb[(kc + 1) & 1], wid, lane);
        asm volatile("" ::: "memory");
        const char* curb = (const char*)Kb[kc & 1];
#pragma unroll
        for (int kb = 0; kb < 4; ++kb) {
            f32x16 acc;
#pragma unroll
            for (int g = 0; g < 4; ++g) {
                half4v bv = *reinterpret_cast<const half4v*>(
                    &biasH[kc * 128 + kb * 32 + g * 8 + hi * 4]);
                acc[4*g+0] = (float)bv[0]; acc[4*g+1] = (float)bv[1];
                acc[4*g+2] = (float)bv[2]; acc[4*g+3] = (float)bv[3];
            }
#pragma unroll
            for (int ks = 0; ks < 4; ++ks) {
                half8 kf = *reinterpret_cast<const half8*>(
                    curb + kb * 4096 + rbK + ((ks * 32 + hi * 16) ^ swK));
                acc = __builtin_amdgcn_mfma_f32_32x32x16_f16(kf, qf[ks], acc, 0, 0, 0);
            }
#pragma unroll
            for (int r = 0; r < 16; ++r) lsum += EXP2F(acc[r]);
        }
        if (kc < 15) {
            asm volatile("s_waitcnt vmcnt(0) lgkmcnt(0)" ::: "memory");
            __builtin_amdgcn_s_barrier();
        }
    }

    // K15 is still resident in Kb[1]; stage V15 now, do softmax math under the load
    stage_tile16k(vtiles + (size_t)15 * 8192, Vb[1], wid, lane);

    lsum += __shfl_xor(lsum, 32, 64);
    const int  rm  = mg[qrow_l];
    const bool uni = (rm != 0) || !(lsum > 0.f);
    const float rscale = uni ? 0.f : 1.f / lsum;
    const float radd   = uni ? (1.0f / 2048.0f) : 0.f;

    f32x16 Oacc0, Oacc1;
#pragma unroll
    for (int r = 0; r < 16; ++r) { Oacc0[r] = 0.f; Oacc1[r] = 0.f; }

    asm volatile("s_waitcnt vmcnt(0) lgkmcnt(0)" ::: "memory");
    __builtin_amdgcn_s_barrier();

    // ================= PHASE 2 (reverse chunks): attn store + O accumulate =========
    float* attnw = attng_ + ((size_t)bh * 2048 + qt * 128 + wid * 32) * 2048;
    for (int kc = 15; kc >= 0; --kc) {
        if (kc > 0) {
            stage_tile16k(ktiles + (size_t)(kc - 1) * 8192, Kb[(kc - 1) & 1], wid, lane);
            stage_tile16k(vtiles + (size_t)(kc - 1) * 8192, Vb[(kc - 1) & 1], wid, lane);
        }
        asm volatile("" ::: "memory");   // keep stage issues ahead of compute/stores
        const char* curKb = (const char*)Kb[kc & 1];
        const char* curVb = (const char*)Vb[kc & 1];
#pragma unroll
        for (int kb = 0; kb < 4; ++kb) {
            // S^T = K.Q (swapped): lane = q (l31), regs = k rows
            f32x16 acc;
#pragma unroll
            for (int g = 0; g < 4; ++g) {
                half4v bv = *reinterpret_cast<const half4v*>(
                    &biasH[kc * 128 + kb * 32 + g * 8 + hi * 4]);
                acc[4*g+0] = (float)bv[0]; acc[4*g+1] = (float)bv[1];
                acc[4*g+2] = (float)bv[2]; acc[4*g+3] = (float)bv[3];
            }
#pragma unroll
            for (int ks = 0; ks < 4; ++ks) {
                half8 kf = *reinterpret_cast<const half8*>(
                    curKb + kb * 4096 + rbK + ((ks * 32 + hi * 16) ^ swK));
                acc = __builtin_amdgcn_mfma_f32_32x32x16_f16(kf, qf[ks], acc, 0, 0, 0);
            }
            // normalized P; reg r holds k = (r&3)+8*(r>>2)+4*hi
            float p[16];
#pragma unroll
            for (int r = 0; r < 16; ++r) p[r] = EXP2F(acc[r]) * rscale + radd;

            // pack to f16 pairs (k-adjacent)
            u32 wA[4], wB[4];
#pragma unroll
            for (int t = 0; t < 4; ++t) {
                wA[t] = pkh(p[4*t],     p[4*t + 1]);
                wB[t] = pkh(p[4*t + 2], p[4*t + 3]);
            }
            // P -> wave-private LDS [q=l31][k] for the store transpose (in-order DS pipe)
#pragma unroll
            for (int t = 0; t < 4; ++t) {
                u32x2 ww; ww[0] = wA[t]; ww[1] = wB[t];
                *reinterpret_cast<u32x2*>(&Pb[wid][l31][t * 8 + 4 * hi]) = ww;
            }

            // PV first — depends only on registers, NOT on the LDS round-trip
#pragma unroll
            for (int s = 0; s < 2; ++s) {
                u32 cA = wA[2*s], dA = wB[2*s], cB = wA[2*s + 1], dB = wB[2*s + 1];
                swap32(cA, cB);
                swap32(dA, dB);
                u32x4 wv; wv[0] = cA; wv[1] = dA; wv[2] = cB; wv[3] = dB;
                half8 af = __builtin_bit_cast(half8, wv);
#pragma unroll
                for (int nd = 0; nd < 2; ++nd) {
                    half8 bf = *reinterpret_cast<const half8*>(
                        curVb + nd * 8192 + rbV +
                        ((kb * 64 + s * 32 + hi * 16) ^ swV));
                    if (nd == 0) Oacc0 = __builtin_amdgcn_mfma_f32_32x32x16_f16(af, bf, Oacc0, 0, 0, 0);
                    else         Oacc1 = __builtin_amdgcn_mfma_f32_32x32x16_f16(af, bf, Oacc1, 0, 0, 0);
                }
            }

            // drain DS (P writes long since retired under PV), then transpose-readback
            // PLAIN (cached) stores this round: let L2 aggregate/smooth the write stream
            asm volatile("s_waitcnt lgkmcnt(0)" ::: "memory");
#pragma unroll
            for (int i8 = 0; i8 < 4; ++i8) {
                int rl = i8 * 8 + (lane >> 3);
                half4v ph = *reinterpret_cast<half4v*>(&Pb[wid][rl][(lane & 7) * 4]);
                f32x4 pf;
                pf[0] = (float)ph[0]; pf[1] = (float)ph[1];
                pf[2] = (float)ph[2]; pf[3] = (float)ph[3];
                *reinterpret_cast<f32x4*>(
                    attnw + (size_t)rl * 2048 + kc * 128 + kb * 32 + (lane & 7) * 4) = pf;
            }
        }
        if (kc > 0) {
            // counted vmcnt: 16 stores issued after the 8 stage loads -> stage complete
            asm volatile("s_waitcnt vmcnt(16) lgkmcnt(0)" ::: "memory");
            __builtin_amdgcn_s_barrier();
        }
    }

    float* outg = outg_ + ((size_t)bh * 2048 + qt * 128) * 64;
#pragma unroll
    for (int r = 0; r < 16; ++r) {
        int q_l = wid * 32 + (r & 3) + 8 * (r >> 2) + 4 * hi;
        __builtin_nontemporal_store(Oacc0[r], outg + (size_t)q_l * 64 + l31);
        __builtin_nontemporal_store(Oacc1[r], outg + (size_t)q_l * 64 + 32 + l31);
    }
}

// ---------------- fallback: previous verified kernel (used if ws too small) ----------------
__global__ __launch_bounds__(256, 2)
void attn_fused(const float* __restrict__ qg_, const float* __restrict__ kg_,
                const float* __restrict__ vg_, const int* __restrict__ mg_,
                float* __restrict__ outg_, float* __restrict__ attng_)
{
    constexpr int N = 2048, D = 64, TM = 128, BK = 128, NCH = 16;
    constexpr int QS = 72, KS = 72, VTS = 136, PS = 72;
    constexpr float INVN = 1.0f / 2048.0f;

    __shared__ _Float16 Qs[TM * QS];
    __shared__ _Float16 Ksh[BK * KS];
    __shared__ _Float16 Vts[D * VTS];
    __shared__ _Float16 Ps[TM * PS];
    __shared__ unsigned char cm[N];

    const int tid  = threadIdx.x;
    const int wid  = tid >> 6;
    const int lane = tid & 63;
    const int quad = lane >> 4;
    const int l15  = lane & 15;

    const int bh = blockIdx.x & 31;
    const int qt = blockIdx.x >> 5;
    const int b  = bh >> 4;

    const float* qg = qg_ + ((size_t)bh * N + qt * TM) * D;
    const float* kg = kg_ + (size_t)bh * N * D;
    const float* vg = vg_ + (size_t)bh * N * D;
    const int*   mg = mg_ + (size_t)b * N;
    float* attng = attng_ + ((size_t)bh * N + (size_t)qt * TM) * N;
    float* outg  = outg_  + ((size_t)bh * N + qt * TM) * D;

#pragma unroll
    for (int i = 0; i < 8; ++i) {
        int f = tid + 256 * i;
        int row = f >> 4, d = (f & 15) * 4;
        float4 x = *reinterpret_cast<const float4*>(qg + (size_t)row * D + d);
        half4v hv;
        hv[0] = (_Float16)(x.x * QSCALE);
        hv[1] = (_Float16)(x.y * QSCALE);
        hv[2] = (_Float16)(x.z * QSCALE);
        hv[3] = (_Float16)(x.w * QSCALE);
        *reinterpret_cast<half4v*>(&Qs[row * QS + d]) = hv;
        cm[f] = (unsigned char)(mg[f] ? 0 : 1);
    }

    float rowm[2][4];
#pragma unroll
    for (int mb = 0; mb < 2; ++mb)
#pragma unroll
        for (int r = 0; r < 4; ++r) {
            int row = qt * TM + wid * 32 + mb * 16 + quad * 4 + r;
            rowm[mb][r] = (float)mg[row];
        }

    __syncthreads();

    half8 qfr[2][2];
#pragma unroll
    for (int mb = 0; mb < 2; ++mb)
#pragma unroll
        for (int ks = 0; ks < 2; ++ks)
            qfr[mb][ks] = *reinterpret_cast<half8*>(
                &Qs[(wid * 32 + mb * 16 + l15) * QS + ks * 32 + quad * 8]);

    float lsum[2][4] = {{0,0,0,0},{0,0,0,0}};

    for (int kc = 0; kc < NCH; ++kc) {
        __syncthreads();
#pragma unroll
        for (int i = 0; i < 8; ++i) {
            int f = tid + 256 * i;
            int row = f >> 4, d = (f & 15) * 4;
            float4 x = *reinterpret_cast<const float4*>(kg + (size_t)(kc * BK + row) * D + d);
            half4v hv;
            hv[0] = (_Float16)x.x; hv[1] = (_Float16)x.y;
            hv[2] = (_Float16)x.z; hv[3] = (_Float16)x.w;
            *reinterpret_cast<half4v*>(&Ksh[row * KS + d]) = hv;
        }
        __syncthreads();

#pragma unroll
        for (int mb = 0; mb < 2; ++mb) {
#pragma unroll
            for (int nb = 0; nb < 8; ++nb) {
                f32x4 acc = {0.f, 0.f, 0.f, 0.f};
#pragma unroll
                for (int ks = 0; ks < 2; ++ks) {
                    half8 bfr = *reinterpret_cast<half8*>(
                        &Ksh[(nb * 16 + l15) * KS + ks * 32 + quad * 8]);
                    acc = __builtin_amdgcn_mfma_f32_16x16x32_f16(qfr[mb][ks], bfr, acc, 0, 0, 0);
                }
                float cmf = (float)cm[kc * BK + nb * 16 + l15];
#pragma unroll
                for (int r = 0; r < 4; ++r)
                    lsum[mb][r] += cmf * EXP2F(acc[r]);
            }
        }
    }

#pragma unroll
    for (int mb = 0; mb < 2; ++mb)
#pragma unroll
        for (int r = 0; r < 4; ++r) {
            float s = lsum[mb][r];
            s += __shfl_xor(s, 1, 64);
            s += __shfl_xor(s, 2, 64);
            s += __shfl_xor(s, 4, 64);
            s += __shfl_xor(s, 8, 64);
            lsum[mb][r] = s;
        }

    float rscale[2][4], radd[2][4];
#pragma unroll
    for (int mb = 0; mb < 2; ++mb)
#pragma unroll
        for (int r = 0; r < 4; ++r) {
            bool uni = (rowm[mb][r] != 0.0f) || !(lsum[mb][r] > 0.0f);
            rscale[mb][r] = uni ? 0.0f : 1.0f / lsum[mb][r];
            radd[mb][r]   = uni ? INVN : 0.0f;
        }

    f32x4 Oacc[2][4];
#pragma unroll
    for (int mb = 0; mb < 2; ++mb)
#pragma unroll
        for (int nd = 0; nd < 4; ++nd)
            Oacc[mb][nd] = (f32x4){0.f, 0.f, 0.f, 0.f};

    for (int kc = 0; kc < NCH; ++kc) {
        __syncthreads();
#pragma unroll
        for (int i = 0; i < 8; ++i) {
            int f = tid + 256 * i;
            int row = f >> 4, d = (f & 15) * 4;
            float4 x = *reinterpret_cast<const float4*>(kg + (size_t)(kc * BK + row) * D + d);
            half4v hv;
            hv[0] = (_Float16)x.x; hv[1] = (_Float16)x.y;
            hv[2] = (_Float16)x.z; hv[3] = (_Float16)x.w;
            *reinterpret_cast<half4v*>(&Ksh[row * KS + d]) = hv;
        }
#pragma unroll
        for (int rr = 0; rr < 4; ++rr) {
            int key0 = rr * 32 + wid * 8;
            half8 hh;
#pragma unroll
            for (int j = 0; j < 8; ++j)
                hh[j] = (_Float16)vg[(size_t)(kc * BK + key0 + j) * D + lane];
            *reinterpret_cast<half8*>(&Vts[lane * VTS + key0]) = hh;
        }
        __syncthreads();

        f32x4 S[2][8];
#pragma unroll
        for (int mb = 0; mb < 2; ++mb)
#pragma unroll
            for (int nb = 0; nb < 8; ++nb) {
                f32x4 acc = {0.f, 0.f, 0.f, 0.f};
#pragma unroll
                for (int ks = 0; ks < 2; ++ks) {
                    half8 bfr = *reinterpret_cast<half8*>(
                        &Ksh[(nb * 16 + l15) * KS + ks * 32 + quad * 8]);
                    acc = __builtin_amdgcn_mfma_f32_16x16x32_f16(qfr[mb][ks], bfr, acc, 0, 0, 0);
                }
                S[mb][nb] = acc;
            }

#pragma unroll
        for (int h = 0; h < 2; ++h) {
#pragma unroll
            for (int nb2 = 0; nb2 < 4; ++nb2) {
                int nb = h * 4 + nb2;
                float cmf = (float)cm[kc * BK + nb * 16 + l15];
#pragma unroll
                for (int mb = 0; mb < 2; ++mb) {
#pragma unroll
                    for (int r = 0; r < 4; ++r) {
                        float p = cmf * EXP2F(S[mb][nb][r]) * rscale[mb][r] + radd[mb][r];
                        Ps[(wid * 32 + mb * 16 + quad * 4 + r) * PS + nb2 * 16 + l15] = (_Float16)p;
                    }
                }
            }
            asm volatile("s_waitcnt lgkmcnt(0)" ::: "memory");

#pragma unroll
            for (int r8 = 0; r8 < 8; ++r8) {
                int rl = r8 * 4 + quad;
                half4v ph = *reinterpret_cast<half4v*>(
                    &Ps[(wid * 32 + rl) * PS + l15 * 4]);
                f32x4 pf;
                pf[0] = (float)ph[0]; pf[1] = (float)ph[1];
                pf[2] = (float)ph[2]; pf[3] = (float)ph[3];
                float* dst = attng + (size_t)(wid * 32 + rl) * N + kc * BK + h * 64 + l15 * 4;
                __builtin_nontemporal_store(pf, reinterpret_cast<f32x4*>(dst));
            }

#pragma unroll
            for (int ks = 0; ks < 2; ++ks) {
                half8 af[2];
#pragma unroll
                for (int mb = 0; mb < 2; ++mb)
                    af[mb] = *reinterpret_cast<half8*>(
                        &Ps[(wid * 32 + mb * 16 + l15) * PS + ks * 32 + quad * 8]);
#pragma unroll
                for (int nd = 0; nd < 4; ++nd) {
                    half8 bfr = *reinterpret_cast<half8*>(
                        &Vts[(nd * 16 + l15) * VTS + h * 64 + ks * 32 + quad * 8]);
#pragma unroll
                    for (int mb = 0; mb < 2; ++mb)
                        Oacc[mb][nd] = __builtin_amdgcn_mfma_f32_16x16x32_f16(af[mb], bfr, Oacc[mb][nd], 0, 0, 0);
                }
            }
        }
    }

#pragma unroll
    for (int mb = 0; mb < 2; ++mb)
#pragma unroll
        for (int nd = 0; nd < 4; ++nd)
#pragma unroll
            for (int r = 0; r < 4; ++r)
                __builtin_nontemporal_store(
                    Oacc[mb][nd][r],
                    outg + (size_t)(wid * 32 + mb * 16 + quad * 4 + r) * D + nd * 16 + l15);
}

// ---------------- launch ----------------
extern "C" void kernel_launch(void* const* d_in, const int* in_sizes, int n_in,
                              void* d_out, int out_size, void* d_ws, size_t ws_size,
                              hipStream_t stream) {
    const float* q   = (const float*)d_in[0];
    const float* k   = (const float*)d_in[1];
    const float* v   = (const float*)d_in[2];
    const int*   msk = (const int*)d_in[3];
    float* out  = (float*)d_out;
    float* attn = out + (size_t)2 * 16 * 2048 * 64;   // output first, then attn

    const size_t kv_halves = (size_t)32 * 2048 * 64;          // per tensor
    const size_t need = kv_halves * 2 * sizeof(_Float16);     // Kws + Vws
    if (d_ws != nullptr && ws_size >= need) {
        _Float16* kws = (_Float16*)d_ws;
        _Float16* vws = kws + kv_halves;
        hipLaunchKernelGGL(prep_kv, dim3(512), dim3(256), 0, stream, k, v, kws, vws);
        hipLaunchKernelGGL(attn_ws, dim3(512), dim3(256), 0, stream,
                           q, kws, vws, msk, out, attn);
    } else {
        hipLaunchKernelGGL(attn_fused, dim3(512), dim3(256), 0, stream,
                           q, k, v, msk, out, attn);
    }
}

// Round 8
// 638.152 us; speedup vs baseline: 1.9414x; 1.0084x over previous
//
#include <hip/hip_runtime.h>

// r7: identical math to r6 but setprio removed (isolate the chunk-rotation variable;
// also changes source hash in case consecutive container failures were build-cache).

typedef _Float16 half8 __attribute__((ext_vector_type(8)));
typedef _Float16 half4v __attribute__((ext_vector_type(4)));
typedef _Float16 half2v __attribute__((ext_vector_type(2)));
typedef float f32x4 __attribute__((ext_vector_type(4)));
typedef float f32x16 __attribute__((ext_vector_type(16)));
typedef unsigned int u32;
typedef u32 u32x2 __attribute__((ext_vector_type(2)));
typedef u32 u32x4 __attribute__((ext_vector_type(4)));
typedef int i32x4 __attribute__((ext_vector_type(4)));

#if __has_builtin(__builtin_amdgcn_exp2f)
#define EXP2F(x) __builtin_amdgcn_exp2f(x)
#else
#define EXP2F(x) exp2f(x)
#endif

#define QSCALE (1.44269504088896340736f * 0.125f)
#define NEGBIG (-16384.0f)

__device__ __forceinline__ void gload_lds16(const void* g, void* l) {
    __builtin_amdgcn_global_load_lds(
        (const __attribute__((address_space(1))) u32*)g,
        (__attribute__((address_space(3))) u32*)l, 16, 0, 0);
}

__device__ __forceinline__ void stage_tile16k(const _Float16* g, _Float16* l,
                                              int wid, int lane) {
#pragma unroll
    for (int i = 0; i < 4; ++i) {
        const int base = (wid * 4 + i) * 1024;
        gload_lds16((const char*)g + base + lane * 16, (char*)l + base);
    }
}

__device__ __forceinline__ u32 pkh(float a, float b) {
    half2v h; h[0] = (_Float16)a; h[1] = (_Float16)b;
    return __builtin_bit_cast(u32, h);
}

__device__ __forceinline__ void swap32(u32 &a, u32 &b) {
    asm volatile("v_permlane32_swap_b32 %0, %1" : "+v"(a), "+v"(b));
}

// K tile 16KB: k-row r, byte c: L = (r>>2)*512 + (r&3)*128 + (c ^ (((r>>2)&7)<<4))
// V tile 16KB: d-row d, byte c: L = (d>>1)*512 + (d&1)*256 + (c ^ (((d>>1)&15)<<4))

__global__ __launch_bounds__(256, 2)
void prep_kv(const float* __restrict__ kg_, const float* __restrict__ vg_,
             _Float16* __restrict__ kws_, _Float16* __restrict__ vws_)
{
    __shared__ float tile[128 * 68];
    const int tid = threadIdx.x;
    const int bh  = blockIdx.x & 31;
    const int kc  = blockIdx.x >> 5;
    const float* kg = kg_ + ((size_t)bh * 2048 + kc * 128) * 64;
    const float* vg = vg_ + ((size_t)bh * 2048 + kc * 128) * 64;
    _Float16* kt = kws_ + ((size_t)bh * 16 + kc) * 8192;
    _Float16* vt = vws_ + ((size_t)bh * 16 + kc) * 8192;

#pragma unroll
    for (int i = 0; i < 8; ++i) {
        int f = tid + 256 * i;
        int r = f >> 4, c4 = f & 15;
        f32x4 x = *reinterpret_cast<const f32x4*>(kg + r * 64 + c4 * 4);
        *reinterpret_cast<f32x4*>(&tile[r * 68 + c4 * 4]) = x;
    }
    __syncthreads();
#pragma unroll
    for (int i = 0; i < 4; ++i) {
        int s16 = tid + 256 * i;
        int R5 = s16 >> 5;
        int r  = R5 * 4 + ((s16 >> 3) & 3);
        int c  = ((s16 & 7) << 4) ^ ((R5 & 7) << 4);
        int d0 = c >> 1;
        f32x4 x0 = *reinterpret_cast<const f32x4*>(&tile[r * 68 + d0]);
        f32x4 x1 = *reinterpret_cast<const f32x4*>(&tile[r * 68 + d0 + 4]);
        half8 h;
#pragma unroll
        for (int j = 0; j < 4; ++j) { h[j] = (_Float16)x0[j]; h[4 + j] = (_Float16)x1[j]; }
        __builtin_nontemporal_store(h, reinterpret_cast<half8*>(kt + s16 * 8));
    }
    __syncthreads();
#pragma unroll
    for (int i = 0; i < 8; ++i) {
        int f = tid + 256 * i;
        int r = f >> 4, c4 = f & 15;
        f32x4 x = *reinterpret_cast<const f32x4*>(vg + r * 64 + c4 * 4);
        *reinterpret_cast<f32x4*>(&tile[r * 68 + c4 * 4]) = x;
    }
    __syncthreads();
#pragma unroll
    for (int i = 0; i < 4; ++i) {
        int s16 = tid + 256 * i;
        int R5 = s16 >> 5;
        int d  = R5 * 2 + ((s16 >> 4) & 1);
        int c  = ((s16 & 15) << 4) ^ ((R5 & 15) << 4);
        int k0 = c >> 1;
        half8 h;
#pragma unroll
        for (int j = 0; j < 8; ++j) h[j] = (_Float16)tile[(k0 + j) * 68 + d];
        __builtin_nontemporal_store(h, reinterpret_cast<half8*>(vt + s16 * 8));
    }
}

// Fused attention. Chunk schedule rotated by qt: the 16 qt-blocks of each bh write
// 16 different 512B column windows at any instant (de-burst the store stream).
__global__ __launch_bounds__(256, 2)
void attn_ws(const float* __restrict__ qg_, const _Float16* __restrict__ kws_,
             const _Float16* __restrict__ vws_, const int* __restrict__ mg_,
             float* __restrict__ outg_, float* __restrict__ attng_)
{
    __shared__ _Float16 Kb[2][8192];
    __shared__ _Float16 Vb[2][8192];
    __shared__ _Float16 biasH[2048];
    __shared__ _Float16 Pb[4][32][36];
    const int tid = threadIdx.x, wid = tid >> 6, lane = tid & 63;
    const int l31 = lane & 31, hi = lane >> 5;
    const int bh = blockIdx.x & 31, qt = blockIdx.x >> 5;
    const int q16 = qt & 15;
    const int* mg = mg_ + (bh >> 4) * 2048;
    const _Float16* ktiles = kws_ + (size_t)bh * 16 * 8192;
    const _Float16* vtiles = vws_ + (size_t)bh * 16 * 8192;
    const int qrow_l = qt * 128 + wid * 32 + l31;

    const float* qrow = qg_ + ((size_t)bh * 2048 + qrow_l) * 64;
    half8 qf[4];
#pragma unroll
    for (int ks = 0; ks < 4; ++ks) {
        f32x4 x0 = *reinterpret_cast<const f32x4*>(qrow + ks * 16 + hi * 8);
        f32x4 x1 = *reinterpret_cast<const f32x4*>(qrow + ks * 16 + hi * 8 + 4);
#pragma unroll
        for (int j = 0; j < 4; ++j) {
            qf[ks][j]     = (_Float16)(x0[j] * QSCALE);
            qf[ks][4 + j] = (_Float16)(x1[j] * QSCALE);
        }
    }
#pragma unroll
    for (int i = 0; i < 2; ++i) {
        int j = (tid + 256 * i) * 4;
        i32x4 m = *reinterpret_cast<const i32x4*>(mg + j);
        half4v bv;
        bv[0] = m[0] ? (_Float16)NEGBIG : (_Float16)0.f;
        bv[1] = m[1] ? (_Float16)NEGBIG : (_Float16)0.f;
        bv[2] = m[2] ? (_Float16)NEGBIG : (_Float16)0.f;
        bv[3] = m[3] ? (_Float16)NEGBIG : (_Float16)0.f;
        *reinterpret_cast<half4v*>(&biasH[j]) = bv;
    }

    stage_tile16k(ktiles + (size_t)q16 * 8192, Kb[0], wid, lane);
    __syncthreads();

    const int rbK = (l31 >> 2) * 512 + (l31 & 3) * 128;
    const int swK = (l31 >> 2) << 4;
    const int rbV = (l31 >> 1) * 512 + (l31 & 1) * 256;
    const int swV = (l31 >> 1) << 4;

    // ---- PHASE 1: row sums, rotated chunk order ----
    float lsum = 0.f;
    for (int t = 0; t < 16; ++t) {
        const int kc = (q16 + t) & 15;
        if (t < 15)
            stage_tile16k(ktiles + (size_t)((q16 + t + 1) & 15) * 8192,
                          Kb[(t + 1) & 1], wid, lane);
        asm volatile("" ::: "memory");
        const char* curb = (const char*)Kb[t & 1];
#pragma unroll
        for (int kb = 0; kb < 4; ++kb) {
            f32x16 acc;
#pragma unroll
            for (int g = 0; g < 4; ++g) {
                half4v bv = *reinterpret_cast<const half4v*>(
                    &biasH[kc * 128 + kb * 32 + g * 8 + hi * 4]);
                acc[4*g+0] = (float)bv[0]; acc[4*g+1] = (float)bv[1];
                acc[4*g+2] = (float)bv[2]; acc[4*g+3] = (float)bv[3];
            }
#pragma unroll
            for (int ks = 0; ks < 4; ++ks) {
                half8 kf = *reinterpret_cast<const half8*>(
                    curb + kb * 4096 + rbK + ((ks * 32 + hi * 16) ^ swK));
                acc = __builtin_amdgcn_mfma_f32_32x32x16_f16(kf, qf[ks], acc, 0, 0, 0);
            }
#pragma unroll
            for (int r = 0; r < 16; ++r) lsum += EXP2F(acc[r]);
        }
        if (t < 15) {
            asm volatile("s_waitcnt vmcnt(0) lgkmcnt(0)" ::: "memory");
            __builtin_amdgcn_s_barrier();
        }
    }

    // last phase-1 chunk is resident in Kb[1]; stage its V under the softmax math
    stage_tile16k(vtiles + (size_t)((q16 + 15) & 15) * 8192, Vb[1], wid, lane);

    lsum += __shfl_xor(lsum, 32, 64);
    const int  rm  = mg[qrow_l];
    const bool uni = (rm != 0) || !(lsum > 0.f);
    const float rscale = uni ? 0.f : 1.f / lsum;
    const float radd   = uni ? (1.0f / 2048.0f) : 0.f;

    f32x16 Oacc0, Oacc1;
#pragma unroll
    for (int r = 0; r < 16; ++r) { Oacc0[r] = 0.f; Oacc1[r] = 0.f; }

    asm volatile("s_waitcnt vmcnt(0) lgkmcnt(0)" ::: "memory");
    __builtin_amdgcn_s_barrier();

    // ---- PHASE 2 (reverse rotated order): attn store + O accumulate ----
    float* attnw = attng_ + ((size_t)bh * 2048 + qt * 128 + wid * 32) * 2048;
    for (int t = 0; t < 16; ++t) {
        const int kc = (q16 + 15 - t) & 15;
        const int cb = (t + 1) & 1;
        if (t < 15) {
            const int nk = (q16 + 14 - t) & 15;
            stage_tile16k(ktiles + (size_t)nk * 8192, Kb[t & 1], wid, lane);
            stage_tile16k(vtiles + (size_t)nk * 8192, Vb[t & 1], wid, lane);
        }
        asm volatile("" ::: "memory");
        const char* curKb = (const char*)Kb[cb];
        const char* curVb = (const char*)Vb[cb];
#pragma unroll
        for (int kb = 0; kb < 4; ++kb) {
            f32x16 acc;
#pragma unroll
            for (int g = 0; g < 4; ++g) {
                half4v bv = *reinterpret_cast<const half4v*>(
                    &biasH[kc * 128 + kb * 32 + g * 8 + hi * 4]);
                acc[4*g+0] = (float)bv[0]; acc[4*g+1] = (float)bv[1];
                acc[4*g+2] = (float)bv[2]; acc[4*g+3] = (float)bv[3];
            }
#pragma unroll
            for (int ks = 0; ks < 4; ++ks) {
                half8 kf = *reinterpret_cast<const half8*>(
                    curKb + kb * 4096 + rbK + ((ks * 32 + hi * 16) ^ swK));
                acc = __builtin_amdgcn_mfma_f32_32x32x16_f16(kf, qf[ks], acc, 0, 0, 0);
            }
            float p[16];
#pragma unroll
            for (int r = 0; r < 16; ++r) p[r] = EXP2F(acc[r]) * rscale + radd;

            u32 wA[4], wB[4];
#pragma unroll
            for (int t4 = 0; t4 < 4; ++t4) {
                wA[t4] = pkh(p[4*t4],     p[4*t4 + 1]);
                wB[t4] = pkh(p[4*t4 + 2], p[4*t4 + 3]);
            }
#pragma unroll
            for (int t4 = 0; t4 < 4; ++t4) {
                u32x2 ww; ww[0] = wA[t4]; ww[1] = wB[t4];
                *reinterpret_cast<u32x2*>(&Pb[wid][l31][t4 * 8 + 4 * hi]) = ww;
            }

            // PV first (register-only inputs)
#pragma unroll
            for (int s = 0; s < 2; ++s) {
                u32 cA = wA[2*s], dA = wB[2*s], cB = wA[2*s + 1], dB = wB[2*s + 1];
                swap32(cA, cB);
                swap32(dA, dB);
                u32x4 wv; wv[0] = cA; wv[1] = dA; wv[2] = cB; wv[3] = dB;
                half8 af = __builtin_bit_cast(half8, wv);
#pragma unroll
                for (int nd = 0; nd < 2; ++nd) {
                    half8 bf = *reinterpret_cast<const half8*>(
                        curVb + nd * 8192 + rbV +
                        ((kb * 64 + s * 32 + hi * 16) ^ swV));
                    if (nd == 0) Oacc0 = __builtin_amdgcn_mfma_f32_32x32x16_f16(af, bf, Oacc0, 0, 0, 0);
                    else         Oacc1 = __builtin_amdgcn_mfma_f32_32x32x16_f16(af, bf, Oacc1, 0, 0, 0);
                }
            }

            asm volatile("s_waitcnt lgkmcnt(0)" ::: "memory");
#pragma unroll
            for (int i8 = 0; i8 < 4; ++i8) {
                int rl = i8 * 8 + (lane >> 3);
                half4v ph = *reinterpret_cast<half4v*>(&Pb[wid][rl][(lane & 7) * 4]);
                f32x4 pf;
                pf[0] = (float)ph[0]; pf[1] = (float)ph[1];
                pf[2] = (float)ph[2]; pf[3] = (float)ph[3];
                *reinterpret_cast<f32x4*>(
                    attnw + (size_t)rl * 2048 + kc * 128 + kb * 32 + (lane & 7) * 4) = pf;
            }
        }
        if (t < 15) {
            asm volatile("s_waitcnt vmcnt(16) lgkmcnt(0)" ::: "memory");
            __builtin_amdgcn_s_barrier();
        }
    }

    float* outg = outg_ + ((size_t)bh * 2048 + qt * 128) * 64;
#pragma unroll
    for (int r = 0; r < 16; ++r) {
        int q_l = wid * 32 + (r & 3) + 8 * (r >> 2) + 4 * hi;
        __builtin_nontemporal_store(Oacc0[r], outg + (size_t)q_l * 64 + l31);
        __builtin_nontemporal_store(Oacc1[r], outg + (size_t)q_l * 64 + 32 + l31);
    }
}

// ---------------- fallback: verified kernel (used if ws too small) ----------------
__global__ __launch_bounds__(256, 2)
void attn_fused(const float* __restrict__ qg_, const float* __restrict__ kg_,
                const float* __restrict__ vg_, const int* __restrict__ mg_,
                float* __restrict__ outg_, float* __restrict__ attng_)
{
    constexpr int N = 2048, D = 64, TM = 128, BK = 128, NCH = 16;
    constexpr int QS = 72, KS = 72, VTS = 136, PS = 72;
    constexpr float INVN = 1.0f / 2048.0f;

    __shared__ _Float16 Qs[TM * QS];
    __shared__ _Float16 Ksh[BK * KS];
    __shared__ _Float16 Vts[D * VTS];
    __shared__ _Float16 Ps[TM * PS];
    __shared__ unsigned char cm[N];

    const int tid  = threadIdx.x;
    const int wid  = tid >> 6;
    const int lane = tid & 63;
    const int quad = lane >> 4;
    const int l15  = lane & 15;

    const int bh = blockIdx.x & 31;
    const int qt = blockIdx.x >> 5;
    const int b  = bh >> 4;

    const float* qg = qg_ + ((size_t)bh * N + qt * TM) * D;
    const float* kg = kg_ + (size_t)bh * N * D;
    const float* vg = vg_ + (size_t)bh * N * D;
    const int*   mg = mg_ + (size_t)b * N;
    float* attng = attng_ + ((size_t)bh * N + (size_t)qt * TM) * N;
    float* outg  = outg_  + ((size_t)bh * N + qt * TM) * D;

#pragma unroll
    for (int i = 0; i < 8; ++i) {
        int f = tid + 256 * i;
        int row = f >> 4, d = (f & 15) * 4;
        float4 x = *reinterpret_cast<const float4*>(qg + (size_t)row * D + d);
        half4v hv;
        hv[0] = (_Float16)(x.x * QSCALE);
        hv[1] = (_Float16)(x.y * QSCALE);
        hv[2] = (_Float16)(x.z * QSCALE);
        hv[3] = (_Float16)(x.w * QSCALE);
        *reinterpret_cast<half4v*>(&Qs[row * QS + d]) = hv;
        cm[f] = (unsigned char)(mg[f] ? 0 : 1);
    }

    float rowm[2][4];
#pragma unroll
    for (int mb = 0; mb < 2; ++mb)
#pragma unroll
        for (int r = 0; r < 4; ++r) {
            int row = qt * TM + wid * 32 + mb * 16 + quad * 4 + r;
            rowm[mb][r] = (float)mg[row];
        }

    __syncthreads();

    half8 qfr[2][2];
#pragma unroll
    for (int mb = 0; mb < 2; ++mb)
#pragma unroll
        for (int ks = 0; ks < 2; ++ks)
            qfr[mb][ks] = *reinterpret_cast<half8*>(
                &Qs[(wid * 32 + mb * 16 + l15) * QS + ks * 32 + quad * 8]);

    float lsum[2][4] = {{0,0,0,0},{0,0,0,0}};

    for (int kc = 0; kc < NCH; ++kc) {
        __syncthreads();
#pragma unroll
        for (int i = 0; i < 8; ++i) {
            int f = tid + 256 * i;
            int row = f >> 4, d = (f & 15) * 4;
            float4 x = *reinterpret_cast<const float4*>(kg + (size_t)(kc * BK + row) * D + d);
            half4v hv;
            hv[0] = (_Float16)x.x; hv[1] = (_Float16)x.y;
            hv[2] = (_Float16)x.z; hv[3] = (_Float16)x.w;
            *reinterpret_cast<half4v*>(&Ksh[row * KS + d]) = hv;
        }
        __syncthreads();

#pragma unroll
        for (int mb = 0; mb < 2; ++mb) {
#pragma unroll
            for (int nb = 0; nb < 8; ++nb) {
                f32x4 acc = {0.f, 0.f, 0.f, 0.f};
#pragma unroll
                for (int ks = 0; ks < 2; ++ks) {
                    half8 bfr = *reinterpret_cast<half8*>(
                        &Ksh[(nb * 16 + l15) * KS + ks * 32 + quad * 8]);
                    acc = __builtin_amdgcn_mfma_f32_16x16x32_f16(qfr[mb][ks], bfr, acc, 0, 0, 0);
                }
                float cmf = (float)cm[kc * BK + nb * 16 + l15];
#pragma unroll
                for (int r = 0; r < 4; ++r)
                    lsum[mb][r] += cmf * EXP2F(acc[r]);
            }
        }
    }

#pragma unroll
    for (int mb = 0; mb < 2; ++mb)
#pragma unroll
        for (int r = 0; r < 4; ++r) {
            float s = lsum[mb][r];
            s += __shfl_xor(s, 1, 64);
            s += __shfl_xor(s, 2, 64);
            s += __shfl_xor(s, 4, 64);
            s += __shfl_xor(s, 8, 64);
            lsum[mb][r] = s;
        }

    float rscale[2][4], radd[2][4];
#pragma unroll
    for (int mb = 0; mb < 2; ++mb)
#pragma unroll
        for (int r = 0; r < 4; ++r) {
            bool uni = (rowm[mb][r] != 0.0f) || !(lsum[mb][r] > 0.0f);
            rscale[mb][r] = uni ? 0.0f : 1.0f / lsum[mb][r];
            radd[mb][r]   = uni ? INVN : 0.0f;
        }

    f32x4 Oacc[2][4];
#pragma unroll
    for (int mb = 0; mb < 2; ++mb)
#pragma unroll
        for (int nd = 0; nd < 4; ++nd)
            Oacc[mb][nd] = (f32x4){0.f, 0.f, 0.f, 0.f};

    for (int kc = 0; kc < NCH; ++kc) {
        __syncthreads();
#pragma unroll
        for (int i = 0; i < 8; ++i) {
            int f = tid + 256 * i;
            int row = f >> 4, d = (f & 15) * 4;
            float4 x = *reinterpret_cast<const float4*>(kg + (size_t)(kc * BK + row) * D + d);
            half4v hv;
            hv[0] = (_Float16)x.x; hv[1] = (_Float16)x.y;
            hv[2] = (_Float16)x.z; hv[3] = (_Float16)x.w;
            *reinterpret_cast<half4v*>(&Ksh[row * KS + d]) = hv;
        }
#pragma unroll
        for (int rr = 0; rr < 4; ++rr) {
            int key0 = rr * 32 + wid * 8;
            half8 hh;
#pragma unroll
            for (int j = 0; j < 8; ++j)
                hh[j] = (_Float16)vg[(size_t)(kc * BK + key0 + j) * D + lane];
            *reinterpret_cast<half8*>(&Vts[lane * VTS + key0]) = hh;
        }
        __syncthreads();

        f32x4 S[2][8];
#pragma unroll
        for (int mb = 0; mb < 2; ++mb)
#pragma unroll
            for (int nb = 0; nb < 8; ++nb) {
                f32x4 acc = {0.f, 0.f, 0.f, 0.f};
#pragma unroll
                for (int ks = 0; ks < 2; ++ks) {
                    half8 bfr = *reinterpret_cast<half8*>(
                        &Ksh[(nb * 16 + l15) * KS + ks * 32 + quad * 8]);
                    acc = __builtin_amdgcn_mfma_f32_16x16x32_f16(qfr[mb][ks], bfr, acc, 0, 0, 0);
                }
                S[mb][nb] = acc;
            }

#pragma unroll
        for (int h = 0; h < 2; ++h) {
#pragma unroll
            for (int nb2 = 0; nb2 < 4; ++nb2) {
                int nb = h * 4 + nb2;
                float cmf = (float)cm[kc * BK + nb * 16 + l15];
#pragma unroll
                for (int mb = 0; mb < 2; ++mb) {
#pragma unroll
                    for (int r = 0; r < 4; ++r) {
                        float p = cmf * EXP2F(S[mb][nb][r]) * rscale[mb][r] + radd[mb][r];
                        Ps[(wid * 32 + mb * 16 + quad * 4 + r) * PS + nb2 * 16 + l15] = (_Float16)p;
                    }
                }
            }
            asm volatile("s_waitcnt lgkmcnt(0)" ::: "memory");

#pragma unroll
            for (int r8 = 0; r8 < 8; ++r8) {
                int rl = r8 * 4 + quad;
                half4v ph = *reinterpret_cast<half4v*>(
                    &Ps[(wid * 32 + rl) * PS + l15 * 4]);
                f32x4 pf;
                pf[0] = (float)ph[0]; pf[1] = (float)ph[1];
                pf[2] = (float)ph[2]; pf[3] = (float)ph[3];
                float* dst = attng + (size_t)(wid * 32 + rl) * N + kc * BK + h * 64 + l15 * 4;
                __builtin_nontemporal_store(pf, reinterpret_cast<f32x4*>(dst));
            }

#pragma unroll
            for (int ks = 0; ks < 2; ++ks) {
                half8 af[2];
#pragma unroll
                for (int mb = 0; mb < 2; ++mb)
                    af[mb] = *reinterpret_cast<half8*>(
                        &Ps[(wid * 32 + mb * 16 + l15) * PS + ks * 32 + quad * 8]);
#pragma unroll
                for (int nd = 0; nd < 4; ++nd) {
                    half8 bfr = *reinterpret_cast<half8*>(
                        &Vts[(nd * 16 + l15) * VTS + h * 64 + ks * 32 + quad * 8]);
#pragma unroll
                    for (int mb = 0; mb < 2; ++mb)
                        Oacc[mb][nd] = __builtin_amdgcn_mfma_f32_16x16x32_f16(af[mb], bfr, Oacc[mb][nd], 0, 0, 0);
                }
            }
        }
    }

#pragma unroll
    for (int mb = 0; mb < 2; ++mb)
#pragma unroll
        for (int nd = 0; nd < 4; ++nd)
#pragma unroll
            for (int r = 0; r < 4; ++r)
                __builtin_nontemporal_store(
                    Oacc[mb][nd][r],
                    outg + (size_t)(wid * 32 + mb * 16 + quad * 4 + r) * D + nd * 16 + l15);
}

// ---------------- launch ----------------
extern "C" void kernel_launch(void* const* d_in, const int* in_sizes, int n_in,
                              void* d_out, int out_size, void* d_ws, size_t ws_size,
                              hipStream_t stream) {
    const float* q   = (const float*)d_in[0];
    const float* k   = (const float*)d_in[1];
    const float* v   = (const float*)d_in[2];
    const int*   msk = (const int*)d_in[3];
    float* out  = (float*)d_out;
    float* attn = out + (size_t)2 * 16 * 2048 * 64;

    const size_t kv_halves = (size_t)32 * 2048 * 64;
    const size_t need = kv_halves * 2 * sizeof(_Float16);
    if (d_ws != nullptr && ws_size >= need) {
        _Float16* kws = (_Float16*)d_ws;
        _Float16* vws = kws + kv_halves;
        hipLaunchKernelGGL(prep_kv, dim3(512), dim3(256), 0, stream, k, v, kws, vws);
        hipLaunchKernelGGL(attn_ws, dim3(512), dim3(256), 0, stream,
                           q, kws, vws, msk, out, attn);
    } else {
        hipLaunchKernelGGL(attn_fused, dim3(512), dim3(256), 0, stream,
                           q, k, v, msk, out, attn);
    }
}